// Round 6
// baseline (296.863 us; speedup 1.0000x reference)
//
#include <hip/hip_runtime.h>

// LocalFeatureAggregation — bf16-MFMA pipeline, point-major activations.
// B=2, N=16384, K=16, D_IN=128, D_OUT=256, GROUPS=16.
//
// Round-12: lse_pool LDS diet 57.5KB -> ~47KB => 3 blocks/CU (24 waves/CU,
// was 2/16). Phase A geo passes go 4x16pt -> 8x8pt (Bbuf 20KB -> 10KB);
// lanes l15 and l15^8 cover complementary k-halves of the same point, so
// the epilogue adds one shfl_xor(8) and only l15<8 lanes write. Everything
// else unchanged from r11 (fusion verified at 289us, swizzle conflicts
// measured at 0.9% of cycles — not the bottleneck; occupancy cap is).

constexpr int Bc = 2;
constexpr int Nc = 16384;
constexpr int Kc = 16;
constexpr float EPSc = 1e-6f;

typedef __attribute__((ext_vector_type(8))) short short8;
typedef __attribute__((ext_vector_type(4))) short short4v;
typedef __attribute__((ext_vector_type(4))) float floatx4;

__device__ inline short f2bf(float x) {
    union { float f; unsigned u; } v; v.f = x;
    unsigned r = v.u + 0x7fffu + ((v.u >> 16) & 1u);
    return (short)(r >> 16);
}
__device__ inline float bf2f(short s) {
    union { unsigned u; float f; } v;
    v.u = ((unsigned)(unsigned short)s) << 16;
    return v.f;
}

// ---- workspace layout ----
// f32 ST[2048]: ST_SC=0, ST_P1=64, ST_P2=128, ST_GEO=256 (B x 65),
//               ST_LP=512: [stage][b][{psc,psh}x128] = 2*512 floats (512..1535)
// then bf16 (short) region, offsets in shorts:
constexpr size_t OW_P1W = 0;                        // 128*256
constexpr size_t OW_P2W = OW_P1W + 128*256;         // 256*256
constexpr size_t OW_M2W = OW_P2W + 256*256;         // 512*256
constexpr size_t OW_SCW = OW_M2W + 512*256;         // 512*128 (sc rows 0..511)
constexpr size_t OW_W1  = OW_SCW + 512*128;         // 128*128 (rows 512..639)
constexpr size_t OW_L1W = OW_W1  + 128*128;         // 128*32 (K padded)
constexpr size_t OW_L2W = OW_L1W + 128*32;          // 128*32
constexpr size_t OW_FB  = OW_L2W + 128*32;          // B*N*128
constexpr size_t OW_X1  = OW_FB  + (size_t)Bc*Nc*128;
constexpr size_t OW_M   = OW_X1  + (size_t)Bc*Nc*128;
constexpr size_t OW_Z1  = OW_M   + (size_t)Bc*Nc*256;
constexpr size_t OW_Z2  = OW_Z1  + (size_t)Bc*Nc*128;
constexpr size_t OW_S   = OW_Z2  + (size_t)Bc*Nc*256;

// prep_kernel segment bounds (elements)
constexpr int CV0 = 128*256;            // pool1_w
constexpr int CV1 = CV0 + 256*256;      // pool2_w
constexpr int CV2 = CV1 + 512*256;      // mlp2_w
constexpr int CV3 = CV2 + 512*128;      // sc_w
constexpr int CV4 = CV3 + 128*128;      // w1
constexpr int CV5 = CV4 + 128*32;       // lse1_w padded
constexpr int CV6 = CV5 + 128*32;       // lse2_w padded
constexpr int CVTOT = CV6 + 512;        // + zero ST[0..511]

__global__ void prep_kernel(const float* __restrict__ p1w,
                            const float* __restrict__ p2w,
                            const float* __restrict__ m2w,
                            const float* __restrict__ scw,
                            const float* __restrict__ w1,
                            const float* __restrict__ l1w,
                            const float* __restrict__ l2w,
                            short* __restrict__ W16,
                            float* __restrict__ ST)
{
    int i = blockIdx.x * 256 + threadIdx.x;
    if (i < CV0) { W16[OW_P1W + i] = f2bf(p1w[i]); return; }
    if (i < CV1) { int k = i - CV0; W16[OW_P2W + k] = f2bf(p2w[k]); return; }
    if (i < CV2) { int k = i - CV1; W16[OW_M2W + k] = f2bf(m2w[k]); return; }
    if (i < CV3) { int k = i - CV2; W16[OW_SCW + k] = f2bf(scw[k]); return; }
    if (i < CV4) { int k = i - CV3; W16[OW_W1  + k] = f2bf(w1[k]); return; }
    if (i < CV5) { int k = i - CV4; int o = k >> 5, c = k & 31;
                   W16[OW_L1W + k] = (c < 10) ? f2bf(l1w[o*10+c]) : (short)0; return; }
    if (i < CV6) { int k = i - CV5; int o = k >> 5, c = k & 31;
                   W16[OW_L2W + k] = (c < 10) ? f2bf(l2w[o*10+c]) : (short)0; return; }
    { int k = i - CV6; if (k < 512) ST[k] = 0.f; }
}

// features f32 [b][128][N] -> FB bf16 [b][N][128]
__global__ void feat_t_kernel(const float* __restrict__ in, short* __restrict__ out) {
    int tid  = threadIdx.x;
    int lane = tid & 63, wave = tid >> 6;
    int bb = blockIdx.x / (Nc / 64);
    int n  = (blockIdx.x % (Nc / 64)) * 64 + lane;
    #pragma unroll
    for (int cc = 0; cc < 4; cc++) {
        int c0 = (wave + cc * 4) * 8;
        short8 sv;
        #pragma unroll
        for (int i = 0; i < 8; i++)
            sv[i] = f2bf(in[((size_t)bb * 128 + c0 + i) * Nc + n]);
        *(short8*)&out[((size_t)(bb * Nc + n)) * 128 + c0] = sv;
    }
}

// Reduce S (10) and Q upper-tri (55) of geo over all (n,k), per batch.
__launch_bounds__(256)
__global__ void geo_reduce_kernel(const float* __restrict__ coords,
                                  const int* __restrict__ knn_idx,
                                  const float* __restrict__ knn_dist,
                                  float* __restrict__ dst)   // [B][65]
{
    __shared__ float part[4][65];
    const int tid  = threadIdx.x;
    const int b    = blockIdx.y;
    const int base = blockIdx.x * 256 + tid;          // gridDim.x = 256
    const float* cb  = coords   + (size_t)b * Nc * 3;
    const int*   ib  = knn_idx  + (size_t)b * Nc * Kc;
    const float* db  = knn_dist + (size_t)b * Nc * Kc;

    float acc[65];
    #pragma unroll
    for (int i = 0; i < 65; i++) acc[i] = 0.f;

    #pragma unroll
    for (int it = 0; it < 4; it++) {
        int r = base + it * 65536;                    // covers Nc*Kc = 262144
        int n = r >> 4;
        float cx = cb[n*3+0], cy = cb[n*3+1], cz = cb[n*3+2];
        int   j  = ib[r];
        float nx = cb[j*3+0], ny = cb[j*3+1], nz = cb[j*3+2];
        float d  = db[r];
        float g[10] = {cx,cy,cz,nx,ny,nz,cx-nx,cy-ny,cz-nz,d};
        #pragma unroll
        for (int c = 0; c < 10; c++) acc[c] += g[c];
        int idx = 10;
        #pragma unroll
        for (int c = 0; c < 10; c++)
            #pragma unroll
            for (int c2 = c; c2 < 10; c2++) acc[idx++] += g[c] * g[c2];
    }
    #pragma unroll
    for (int i = 0; i < 65; i++) {
        float v = acc[i];
        #pragma unroll
        for (int off = 1; off < 64; off <<= 1) v += __shfl_xor(v, off);
        acc[i] = v;
    }
    int lane = tid & 63, wave = tid >> 6;
    if (lane == 0) {
        #pragma unroll
        for (int i = 0; i < 65; i++) part[wave][i] = acc[i];
    }
    __syncthreads();
    if (tid < 65) {
        float s = part[0][tid] + part[1][tid] + part[2][tid] + part[3][tid];
        atomicAdd(&dst[b * 65 + tid], s);
    }
}

// Closed-form geo-GN params: for (stage s, batch b, channel o):
//   sum_y = NK*bias + w.S ; sum_y2 = NK*b^2 + 2b(w.S) + w^T Q w
//   group (8ch) mean/var -> pscale = iv*gw, pshift = (bias-mu)*pscale + gb.
// One block, 512 threads = (s,b,o).
__launch_bounds__(512)
__global__ void lse_param_kernel(const float* __restrict__ geoS,  // [B][65]
                                 const float* __restrict__ l1w,
                                 const float* __restrict__ l1b,
                                 const float* __restrict__ l1gw,
                                 const float* __restrict__ l1gb,
                                 const float* __restrict__ l2w,
                                 const float* __restrict__ l2b,
                                 const float* __restrict__ l2gw,
                                 const float* __restrict__ l2gb,
                                 float* __restrict__ lp)          // ST+512
{
    __shared__ float osum[512], osq[512];
    const int tid = threadIdx.x;
    const int s = tid >> 8, r = tid & 255, b = r >> 7, o = r & 127;
    const float* wf = s ? l2w : l1w;
    const float* bf = s ? l2b : l1b;
    const float* gwf = s ? l2gw : l1gw;
    const float* gbf = s ? l2gb : l1gb;
    const float NK = (float)(Nc * Kc);
    const float* S = geoS + b * 65;

    float w[10];
    #pragma unroll
    for (int c = 0; c < 10; c++) w[c] = wf[o * 10 + c];
    float wS = 0.f;
    #pragma unroll
    for (int c = 0; c < 10; c++) wS += w[c] * S[c];
    float q = 0.f;
    {
        int idx = 10;
        #pragma unroll
        for (int c = 0; c < 10; c++)
            #pragma unroll
            for (int c2 = c; c2 < 10; c2++) {
                float t = w[c] * w[c2] * S[idx++];
                q += (c == c2) ? t : 2.f * t;
            }
    }
    float bo = bf[o];
    osum[tid] = NK * bo + wS;
    osq[tid]  = NK * bo * bo + 2.f * bo * wS + q;
    __syncthreads();
    int gb0 = tid & ~7;
    float gs = 0.f, gq = 0.f;
    #pragma unroll
    for (int i = 0; i < 8; i++) { gs += osum[gb0 + i]; gq += osq[gb0 + i]; }
    float cnt  = 8.f * NK;
    float mean = gs / cnt;
    float var  = gq / cnt - mean * mean;
    float iv   = rsqrtf(var + EPSc);
    float psc  = iv * gwf[o];
    float psh  = (bo - mean) * psc + gbf[o];
    lp[s * 512 + b * 256 + o]       = psc;
    lp[s * 512 + b * 256 + 128 + o] = psh;
}

// GEMM: out[b][n][o] = sum_c W[o][c] * X[b][n][c] + bias[o]   (point-major)
// MODE 3: final — B normalized in staging (pool2 GN+relu), epilogue
//         v + GN(sbuf) -> leaky 0.01 -> f32 [b][o][n].
// MODE 4: merged sc(512, raw+stats)/mlp1(128, leaky0.2) by mo tile.
// BK=64 (2 x 32-K MFMA slices per staging pass), stride 68.
template<int CIN, int COUT, int GROUP_CH, int MODE>
__launch_bounds__(256)
__global__ void gemm_conv(const short* __restrict__ wA,   // [COUT][CIN] bf16
                          const short* __restrict__ xB,   // [b][N][CIN] bf16
                          const float* __restrict__ bias,
                          short* __restrict__ outb,
                          float* __restrict__ outf,
                          float* __restrict__ stats,
                          const short* __restrict__ sbuf, // [b][N][512] bf16
                          const float* __restrict__ st_sc,
                          const float* __restrict__ gw,
                          const float* __restrict__ gb,
                          float sc_cnt,
                          const float* __restrict__ bst,  // MODE 3: pool2 stats
                          const float* __restrict__ bgw,
                          const float* __restrict__ bgb,
                          float bcnt,
                          const float* __restrict__ bias2, // MODE 4: mlp1 bias
                          short* __restrict__ outb2)       // MODE 4: X1 out
{
    __shared__ short Abuf[128 * 68];
    __shared__ short Bbuf[128 * 68];
    __shared__ float sstat[32];
    __shared__ float smean[4], sinv[4];
    __shared__ float bsc[256], bsh[256];

    const int tid  = threadIdx.x;
    const int n0   = blockIdx.x * 128;
    const int mo   = blockIdx.y * 128;
    const int b    = blockIdx.z;
    const int lane = tid & 63;
    const int wave = tid >> 6;
    const int wm   = (wave >> 1) * 64;
    const int wn   = (wave & 1) * 64;
    const int l15  = lane & 15;
    const int quad = lane >> 4;
    const bool sc_tile = (MODE == 4) && (mo < 512);

    if constexpr (MODE == 2 || MODE == 4) { if (tid < 32) sstat[tid] = 0.f; }
    if constexpr (MODE == 3) {
        if (tid < 4) {
            int g = (mo >> 5) + tid;
            float s0 = st_sc[(b * 16 + g) * 2 + 0];
            float s1 = st_sc[(b * 16 + g) * 2 + 1];
            float mean = s0 / sc_cnt;
            float var  = s1 / sc_cnt - mean * mean;
            smean[tid] = mean;
            sinv[tid]  = rsqrtf(var + EPSc);
        }
        if (tid < CIN) {   // pool2 GN: 256 ch, 16 ch/group
            int g = tid >> 4;
            float s0 = bst[(b * 16 + g) * 2 + 0];
            float s1 = bst[(b * 16 + g) * 2 + 1];
            float mean = s0 / bcnt;
            float var  = s1 / bcnt - mean * mean;
            float inv  = rsqrtf(var + EPSc);
            float sc_  = inv * bgw[tid];
            bsc[tid] = sc_;
            bsh[tid] = bgb[tid] - mean * sc_;
        }
    }

    floatx4 acc[4][4];
    #pragma unroll
    for (int mi = 0; mi < 4; mi++)
        #pragma unroll
        for (int ni = 0; ni < 4; ni++)
            acc[mi][ni] = (floatx4){0.f, 0.f, 0.f, 0.f};

    const short* wAr = wA + (size_t)mo * CIN;
    const short* xBr = xB + (size_t)b * Nc * CIN + (size_t)n0 * CIN;

    for (int c0 = 0; c0 < CIN; c0 += 64) {
        __syncthreads();
        #pragma unroll
        for (int s = 0; s < 4; s++) {
            int e = tid + s * 256;
            int r = e >> 3, q = e & 7;
            *(short8*)&Abuf[r * 68 + q * 8] =
                *(const short8*)(wAr + (size_t)r * CIN + c0 + q * 8);
            short8 v = *(const short8*)(xBr + (size_t)r * CIN + c0 + q * 8);
            if constexpr (MODE == 3) {
                #pragma unroll
                for (int i = 0; i < 8; i++) {
                    int ch = c0 + q * 8 + i;
                    float t = bf2f(v[i]) * bsc[ch] + bsh[ch];
                    v[i] = f2bf(t > 0.f ? t : 0.f);
                }
            }
            *(short8*)&Bbuf[r * 68 + q * 8] = v;
        }
        __syncthreads();

        #pragma unroll
        for (int kk = 0; kk < 2; kk++) {
            short8 af[4], bfr[4];
            #pragma unroll
            for (int mi = 0; mi < 4; mi++)
                af[mi] = *(short8*)&Abuf[(wm + mi * 16 + l15) * 68 + kk * 32 + quad * 8];
            #pragma unroll
            for (int ni = 0; ni < 4; ni++)
                bfr[ni] = *(short8*)&Bbuf[(wn + ni * 16 + l15) * 68 + kk * 32 + quad * 8];
            #pragma unroll
            for (int mi = 0; mi < 4; mi++)
                #pragma unroll
                for (int ni = 0; ni < 4; ni++)
                    acc[mi][ni] = __builtin_amdgcn_mfma_f32_16x16x32_bf16(
                        af[mi], bfr[ni], acc[mi][ni], 0, 0, 0);
        }
    }

    // D row(o) = mo+wm+mi*16+quad*4+r, col(n) = n0+wn+ni*16+l15
    #pragma unroll
    for (int mi = 0; mi < 4; mi++) {
        int rowl = wm + mi * 16 + quad * 4;
        float b4[4], gw4[4], gb4[4];
        #pragma unroll
        for (int r = 0; r < 4; r++) {
            if constexpr (MODE == 4) {
                b4[r] = sc_tile ? bias[mo + rowl + r] : bias2[mo - 512 + rowl + r];
            } else {
                b4[r] = bias[mo + rowl + r];
            }
            if constexpr (MODE == 3) {
                gw4[r] = gw[mo + rowl + r];
                gb4[r] = gb[mo + rowl + r];
            }
        }
        float gs = 0.f, gq = 0.f;
        #pragma unroll
        for (int ni = 0; ni < 4; ni++) {
            int col = n0 + wn + ni * 16 + l15;
            if constexpr (MODE == 3) {
                short4v s4 = *(const short4v*)&sbuf[((size_t)(b * Nc + col)) * 512 + mo + rowl];
                int gl = rowl >> 5;
                #pragma unroll
                for (int r = 0; r < 4; r++) {
                    float v = acc[mi][ni][r] + b4[r];
                    float s = bf2f(s4[r]);
                    float sn = (s - smean[gl]) * sinv[gl] * gw4[r] + gb4[r];
                    float o = v + sn;
                    o = o > 0.f ? o : 0.01f * o;
                    outf[((size_t)b * COUT + mo + rowl + r) * Nc + col] = o;
                }
            } else if constexpr (MODE == 4) {
                short4v sv;
                #pragma unroll
                for (int r = 0; r < 4; r++) {
                    float v = acc[mi][ni][r] + b4[r];
                    if (sc_tile) { gs += v; gq += v * v; }
                    else v = v > 0.f ? v : 0.2f * v;
                    sv[r] = f2bf(v);
                }
                if (sc_tile)
                    *(short4v*)&outb[((size_t)(b * Nc + col)) * 512 + mo + rowl] = sv;
                else
                    *(short4v*)&outb2[((size_t)(b * Nc + col)) * 128 + mo - 512 + rowl] = sv;
            } else {
                short4v sv;
                #pragma unroll
                for (int r = 0; r < 4; r++) {
                    float v = acc[mi][ni][r] + b4[r];
                    if constexpr (MODE == 1) v = v > 0.f ? v : 0.2f * v;
                    if constexpr (MODE == 2) { gs += v; gq += v * v; }
                    sv[r] = f2bf(v);
                }
                *(short4v*)&outb[((size_t)(b * Nc + col)) * COUT + mo + rowl] = sv;
            }
        }
        if ((MODE == 2) || (MODE == 4 && sc_tile)) {
            #pragma unroll
            for (int off = 1; off < 16; off <<= 1) {
                gs += __shfl_xor(gs, off);
                gq += __shfl_xor(gq, off);
            }
            if (l15 == 0) {
                int gl = rowl / GROUP_CH;
                atomicAdd(&sstat[gl * 2 + 0], gs);
                atomicAdd(&sstat[gl * 2 + 1], gq);
            }
        }
    }
    if ((MODE == 2) || (MODE == 4 && sc_tile)) {
        __syncthreads();
        constexpr int NG = 128 / GROUP_CH;
        if (tid < 2 * NG) {
            int g0 = mo / GROUP_CH;
            atomicAdd(&stats[b * 32 + (g0 + (tid >> 1)) * 2 + (tid & 1)], sstat[tid]);
        }
    }
}

// Fused LSE + pool: 64-point tile, 512 threads (8 waves).
//  A) geo conv (MFMA, precomputed GN) + relu + mean_k  -> m_lds[p][0:128]
//     (8 passes x 8 points; Bbuf = 128 cols = 10KB; lanes l15/l15^8 hold
//      complementary k-halves -> shfl_xor(8) combine, l15<8 writes)
//  B) neighbor gather-mean (opt. folded prev-pool GN)  -> m_lds[p][128:256]
//  C) pool GEMM (PCOUT x 64 x 256) from m_lds, A-frags straight from L2,
//     raw bf16 out + group-stats atomics.
// m_lds channel-groups XOR-swizzled (g ^= p&7) -> all LDS phases <=2-way.
// Total static LDS ~47KB -> 3 blocks/CU = 24 waves/CU (was 2/16).
// PCOUT: 128 (pool1, group 8) / 256 (pool2, group 16).
template<int PCOUT, int PGROUP>
__launch_bounds__(512)
__global__ void lse_pool_kernel(const float* __restrict__ coords,
                                const int* __restrict__ knn_idx,
                                const float* __restrict__ knn_dist,
                                const short* __restrict__ xprev, // [b][N][128]
                                const short* __restrict__ wpad,  // [128][32]
                                const float* __restrict__ lp,    // geo GN params
                                const float* __restrict__ xst,   // prev stats or null
                                const float* __restrict__ xgw,
                                const float* __restrict__ xgb,
                                float xcnt,
                                const short* __restrict__ pw,    // [PCOUT][256]
                                const float* __restrict__ pb,    // [PCOUT]
                                float* __restrict__ stats,       // [B][32]
                                short* __restrict__ z)           // [b][N][PCOUT]
{
    __shared__ short Bbuf[128 * 40];        // 10 KB: one 8-pt geo sub-tile
    __shared__ short mld[64 * 256];         // 32 KB: m rows, group-swizzled
    __shared__ int   jl[1024];              // [k][p]
    __shared__ float xscs[128], xshs[128];
    __shared__ float sstat[32];

    const int tid = threadIdx.x;
    const int b   = blockIdx.x >> 8;        // Nc/64 = 256 blocks per batch
    const int n0  = (blockIdx.x & 255) * 64;
    const bool norm = (xst != nullptr);
    const int lane = tid & 63, wave = tid >> 6;
    const int l15 = lane & 15, quad = lane >> 4;

    if (tid < 32) sstat[tid] = 0.f;
    if (norm && tid < 128) {                // prev-pool GN fold: 8 ch/group
        int g = tid >> 3;
        float s0 = xst[(b * 16 + g) * 2 + 0];
        float s1 = xst[(b * 16 + g) * 2 + 1];
        float mean = s0 / xcnt;
        float var  = s1 / xcnt - mean * mean;
        float inv  = rsqrtf(var + EPSc);
        float sc_  = inv * xgw[tid];
        xscs[tid] = sc_;
        xshs[tid] = xgb[tid] - mean * sc_;
    }

    // hoisted geo A-frag + GN params (o-tile = wave; 8 waves x 16 = 128 ch)
    short8 af = *(const short8*)(wpad + (wave * 16 + l15) * 32 + quad * 8);
    floatx4 psc = *(const floatx4*)&lp[b * 256 + wave * 16 + quad * 4];
    floatx4 psh = *(const floatx4*)&lp[b * 256 + 128 + wave * 16 + quad * 4];

    const float* cb = coords + (size_t)b * Nc * 3;

    // ---- phase A: geo conv + relu + mean_k -> mld[p][0:128] ----
    #pragma unroll
    for (int pass = 0; pass < 8; pass++) {
        if (tid < 128) {   // build 128 cols (8 points x 16 k): col = tid
            int ptl = tid & 7, k = tid >> 3;
            int p = pass * 8 + ptl;
            int n = n0 + p;
            float cx = cb[n*3+0], cy = cb[n*3+1], cz = cb[n*3+2];
            int   j  = knn_idx[((size_t)b * Nc + n) * Kc + k];
            float nx = cb[j*3+0], ny = cb[j*3+1], nz = cb[j*3+2];
            float d  = knn_dist[((size_t)b * Nc + n) * Kc + k];
            int col = k * 8 + ptl;
            short8 w0, w1, zz;
            w0[0]=f2bf(cx); w0[1]=f2bf(cy); w0[2]=f2bf(cz);
            w0[3]=f2bf(nx); w0[4]=f2bf(ny); w0[5]=f2bf(nz);
            w0[6]=f2bf(cx-nx); w0[7]=f2bf(cy-ny);
            w1[0]=f2bf(cz-nz); w1[1]=f2bf(d);
            #pragma unroll
            for (int i = 2; i < 8; i++) w1[i] = 0;
            #pragma unroll
            for (int i = 0; i < 8; i++) zz[i] = 0;
            *(short8*)&Bbuf[col * 40 + 0]  = w0;
            *(short8*)&Bbuf[col * 40 + 8]  = w1;
            *(short8*)&Bbuf[col * 40 + 16] = zz;
            *(short8*)&Bbuf[col * 40 + 24] = zz;
            jl[k * 64 + p] = j;
        }
        __syncthreads();
        {
            // col = nb*32 + half*16 + l15 -> pt = l15&7, k = nb*4+half*2+(l15>>3)
            float s4[4] = {0.f, 0.f, 0.f, 0.f};
            #pragma unroll
            for (int nb = 0; nb < 4; nb++) {
                short8 f0 = *(short8*)&Bbuf[(nb*32 + 0*16 + l15) * 40 + quad * 8];
                short8 f1 = *(short8*)&Bbuf[(nb*32 + 1*16 + l15) * 40 + quad * 8];
                floatx4 a0 = __builtin_amdgcn_mfma_f32_16x16x32_bf16(
                    af, f0, (floatx4){0.f, 0.f, 0.f, 0.f}, 0, 0, 0);
                floatx4 a1 = __builtin_amdgcn_mfma_f32_16x16x32_bf16(
                    af, f1, (floatx4){0.f, 0.f, 0.f, 0.f}, 0, 0, 0);
                #pragma unroll
                for (int r = 0; r < 4; r++) {
                    float v0 = a0[r] * psc[r] + psh[r];
                    float v1 = a1[r] * psc[r] + psh[r];
                    s4[r] += (v0 > 0.f ? v0 : 0.f) + (v1 > 0.f ? v1 : 0.f);
                }
            }
            // lanes l15 and l15^8 hold complementary k-halves of point l15&7
            #pragma unroll
            for (int r = 0; r < 4; r++) s4[r] += __shfl_xor(s4[r], 8);
            if (l15 < 8) {
                int p = pass * 8 + l15;
                int g = wave * 2 + (quad >> 1);      // ch group (0..15)
                short4v sv;
                #pragma unroll
                for (int r = 0; r < 4; r++) sv[r] = f2bf(s4[r] * (1.f / 16.f));
                *(short4v*)&mld[p * 256 + ((g ^ (p & 7)) << 3) + (quad & 1) * 4] = sv;
            }
        }
        __syncthreads();
    }

    // ---- phase B: gather-mean -> mld[p][128:256] (jl complete) ----
    {
        const int tp = tid >> 4, cs = tid & 15;     // tp in [0,32)
        float sc8[8], sh8[8];
        if (norm) {
            #pragma unroll
            for (int i = 0; i < 8; i++) { sc8[i] = xscs[cs*8+i]; sh8[i] = xshs[cs*8+i]; }
        }
        #pragma unroll
        for (int pp = 0; pp < 2; pp++) {
            int p = tp + pp * 32;
            float acc8[8];
            #pragma unroll
            for (int i = 0; i < 8; i++) acc8[i] = 0.f;
            #pragma unroll
            for (int k = 0; k < 16; k++) {
                int j = jl[k * 64 + p];
                short8 v = *(const short8*)&xprev[((size_t)(b * Nc + j)) * 128 + cs * 8];
                if (norm) {
                    #pragma unroll
                    for (int i = 0; i < 8; i++) {
                        float t = bf2f(v[i]) * sc8[i] + sh8[i];
                        acc8[i] += t > 0.f ? t : 0.f;
                    }
                } else {
                    #pragma unroll
                    for (int i = 0; i < 8; i++) acc8[i] += bf2f(v[i]);
                }
            }
            short8 sv;
            #pragma unroll
            for (int i = 0; i < 8; i++) sv[i] = f2bf(acc8[i] * (1.f / 16.f));
            int g = 16 + cs;
            *(short8*)&mld[p * 256 + ((g ^ (p & 7)) << 3)] = sv;
        }
    }
    __syncthreads();

    // ---- phase C: pool GEMM (PCOUT x 64pts x 256ch) ----
    constexpr int NOT = PCOUT / 128;               // o-tiles per wave (1 or 2)
    #pragma unroll
    for (int oi = 0; oi < NOT; oi++) {
        const int ot = wave + oi * 8;
        short8 afk[8];
        #pragma unroll
        for (int ks = 0; ks < 8; ks++)
            afk[ks] = *(const short8*)(pw + ((size_t)(ot * 16 + l15)) * 256 + ks * 32 + quad * 8);
        floatx4 acc[4];
        #pragma unroll
        for (int nt = 0; nt < 4; nt++) acc[nt] = (floatx4){0.f, 0.f, 0.f, 0.f};
        #pragma unroll
        for (int ks = 0; ks < 8; ks++) {
            #pragma unroll
            for (int nt = 0; nt < 4; nt++) {
                int p = nt * 16 + l15;
                int g = ks * 4 + quad;
                short8 bfr = *(short8*)&mld[p * 256 + ((g ^ (p & 7)) << 3)];
                acc[nt] = __builtin_amdgcn_mfma_f32_16x16x32_bf16(
                    afk[ks], bfr, acc[nt], 0, 0, 0);
            }
        }
        floatx4 b4 = *(const floatx4*)&pb[ot * 16 + quad * 4];
        float gs = 0.f, gq = 0.f;
        #pragma unroll
        for (int nt = 0; nt < 4; nt++) {
            int col = n0 + nt * 16 + l15;
            short4v sv;
            #pragma unroll
            for (int r = 0; r < 4; r++) {
                float v = acc[nt][r] + b4[r];
                gs += v; gq += v * v;
                sv[r] = f2bf(v);
            }
            *(short4v*)&z[((size_t)(b * Nc + col)) * PCOUT + ot * 16 + quad * 4] = sv;
        }
        #pragma unroll
        for (int off = 1; off < 16; off <<= 1) {
            gs += __shfl_xor(gs, off);
            gq += __shfl_xor(gq, off);
        }
        if (l15 == 0) {
            int gl = (ot * 16 + quad * 4) / PGROUP;
            atomicAdd(&sstat[gl * 2 + 0], gs);
            atomicAdd(&sstat[gl * 2 + 1], gq);
        }
    }
    __syncthreads();
    if (tid < 32) atomicAdd(&stats[b * 32 + tid], sstat[tid]);
}

extern "C" void kernel_launch(void* const* d_in, const int* in_sizes, int n_in,
                              void* d_out, int out_size, void* d_ws, size_t ws_size,
                              hipStream_t stream)
{
    const float* coords   = (const float*)d_in[0];
    const float* features = (const float*)d_in[1];
    const float* knn_dist = (const float*)d_in[2];
    const int*   knn_idx  = (const int*)  d_in[3];
    const float* w1       = (const float*)d_in[4];
    const float* b1       = (const float*)d_in[5];
    const float* lse1_w   = (const float*)d_in[6];
    const float* lse1_b   = (const float*)d_in[7];
    const float* lse1_gw  = (const float*)d_in[8];
    const float* lse1_gb  = (const float*)d_in[9];
    const float* pool1_w  = (const float*)d_in[10];
    const float* pool1_b  = (const float*)d_in[11];
    const float* pool1_gw = (const float*)d_in[12];
    const float* pool1_gb = (const float*)d_in[13];
    const float* lse2_w   = (const float*)d_in[14];
    const float* lse2_b   = (const float*)d_in[15];
    const float* lse2_gw  = (const float*)d_in[16];
    const float* lse2_gb  = (const float*)d_in[17];
    const float* pool2_w  = (const float*)d_in[18];
    const float* pool2_b  = (const float*)d_in[19];
    const float* pool2_gw = (const float*)d_in[20];
    const float* pool2_gb = (const float*)d_in[21];
    const float* mlp2_w   = (const float*)d_in[22];
    const float* mlp2_b   = (const float*)d_in[23];
    const float* sc_w     = (const float*)d_in[24];
    const float* sc_b     = (const float*)d_in[25];
    const float* sc_gw    = (const float*)d_in[26];
    const float* sc_gb    = (const float*)d_in[27];
    (void)in_sizes; (void)n_in; (void)out_size; (void)ws_size;

    float* ST = (float*)d_ws;           // 2048 floats
    float* ST_SC  = ST + 0;
    float* ST_P1  = ST + 64;
    float* ST_P2  = ST + 128;
    float* ST_GEO = ST + 256;           // B x 65
    float* ST_LP  = ST + 512;           // [stage][b][{psc,psh}x128]
    short* W16 = (short*)(ST + 2048);
    short* P1Wb = W16 + OW_P1W;
    short* P2Wb = W16 + OW_P2W;
    short* M2Wb = W16 + OW_M2W;
    short* SCWb = W16 + OW_SCW;         // rows 0..511 sc, 512..639 w1
    short* L1Wb = W16 + OW_L1W;
    short* L2Wb = W16 + OW_L2W;
    short* FB   = W16 + OW_FB;
    short* X1B  = W16 + OW_X1;
    short* Z1   = W16 + OW_Z1;
    short* Z2   = W16 + OW_Z2;
    short* SB   = W16 + OW_S;
    float* out  = (float*)d_out;

    prep_kernel<<<(CVTOT + 255) / 256, 256, 0, stream>>>(
        pool1_w, pool2_w, mlp2_w, sc_w, w1, lse1_w, lse2_w, W16, ST);
    feat_t_kernel<<<Bc * Nc / 64, 256, 0, stream>>>(features, FB);
    geo_reduce_kernel<<<dim3(256, Bc), 256, 0, stream>>>(
        coords, knn_idx, knn_dist, ST_GEO);
    lse_param_kernel<<<1, 512, 0, stream>>>(
        ST_GEO, lse1_w, lse1_b, lse1_gw, lse1_gb,
        lse2_w, lse2_b, lse2_gw, lse2_gb, ST_LP);

    // merged sc (512, raw bf16 + stats, group=32ch) + mlp1 (128, leaky 0.2)
    gemm_conv<128,640,32,4><<<dim3(Nc/128, 5, Bc), 256, 0, stream>>>(
        SCWb, FB, sc_b, SB, nullptr, ST_SC, nullptr, nullptr, nullptr, nullptr, 0.f,
        nullptr, nullptr, nullptr, 0.f, b1, X1B);
    // fused lse1 + pool1 (128 out, group 8): X1B gather raw, stats -> ST_P1
    lse_pool_kernel<128,8><<<Bc * Nc / 64, 512, 0, stream>>>(
        coords, knn_idx, knn_dist, X1B, L1Wb, ST_LP,
        nullptr, nullptr, nullptr, 0.f,
        P1Wb, pool1_b, ST_P1, Z1);
    // fused lse2 + pool2 (256 out, group 16): Z1 gather + pool1-GN fold,
    // stats -> ST_P2
    lse_pool_kernel<256,16><<<Bc * Nc / 64, 512, 0, stream>>>(
        coords, knn_idx, knn_dist, Z1, L2Wb, ST_LP + 512,
        ST_P1, pool1_gw, pool1_gb, (float)(8 * Nc),
        P2Wb, pool2_b, ST_P2, Z2);
    // final: mlp2(GN+relu(Z2) folded into staging) + GN(S) -> leaky 0.01 -> f32
    gemm_conv<256,512,32,3><<<dim3(Nc/128, 4, Bc), 256, 0, stream>>>(
        M2Wb, Z2, mlp2_b, nullptr, out, nullptr, SB, ST_SC, sc_gw, sc_gb,
        (float)(32 * Nc), ST_P2, pool2_gw, pool2_gb, (float)(16 * Nc),
        nullptr, nullptr);
}

// Round 7
// 293.126 us; speedup vs baseline: 1.0127x; 1.0127x over previous
//
#include <hip/hip_runtime.h>

// LocalFeatureAggregation — bf16-MFMA pipeline, point-major activations.
// B=2, N=16384, K=16, D_IN=128, D_OUT=256, GROUPS=16.
//
// Round-13: lse_pool point tile 64 -> 32 (grid 512 -> 1024 blocks = 4
// blocks/CU). r12's LDS diet missed that occupancy was GRID-limited (512
// blocks / 256 CUs = 2/CU), not LDS-limited. Phase A reverted to the r11
// 16-pt-pass structure (r12's 8-pass+shfl variant measured -7%: 42->45us).
// LDS = 20KB Bbuf + 16KB mld + 2KB jl + 1.2KB misc = 39.1KB -> 4 blocks/CU
// fits both LDS and grid. Pool-weight L2 re-reads double (+96MB ~ +3us
// aggregate) — absorbed if occupancy pays. gemm_conv untouched.

constexpr int Bc = 2;
constexpr int Nc = 16384;
constexpr int Kc = 16;
constexpr float EPSc = 1e-6f;

typedef __attribute__((ext_vector_type(8))) short short8;
typedef __attribute__((ext_vector_type(4))) short short4v;
typedef __attribute__((ext_vector_type(4))) float floatx4;

__device__ inline short f2bf(float x) {
    union { float f; unsigned u; } v; v.f = x;
    unsigned r = v.u + 0x7fffu + ((v.u >> 16) & 1u);
    return (short)(r >> 16);
}
__device__ inline float bf2f(short s) {
    union { unsigned u; float f; } v;
    v.u = ((unsigned)(unsigned short)s) << 16;
    return v.f;
}

// ---- workspace layout ----
// f32 ST[2048]: ST_SC=0, ST_P1=64, ST_P2=128, ST_GEO=256 (B x 65),
//               ST_LP=512: [stage][b][{psc,psh}x128] = 2*512 floats (512..1535)
// then bf16 (short) region, offsets in shorts:
constexpr size_t OW_P1W = 0;                        // 128*256
constexpr size_t OW_P2W = OW_P1W + 128*256;         // 256*256
constexpr size_t OW_M2W = OW_P2W + 256*256;         // 512*256
constexpr size_t OW_SCW = OW_M2W + 512*256;         // 512*128 (sc rows 0..511)
constexpr size_t OW_W1  = OW_SCW + 512*128;         // 128*128 (rows 512..639)
constexpr size_t OW_L1W = OW_W1  + 128*128;         // 128*32 (K padded)
constexpr size_t OW_L2W = OW_L1W + 128*32;          // 128*32
constexpr size_t OW_FB  = OW_L2W + 128*32;          // B*N*128
constexpr size_t OW_X1  = OW_FB  + (size_t)Bc*Nc*128;
constexpr size_t OW_M   = OW_X1  + (size_t)Bc*Nc*128;
constexpr size_t OW_Z1  = OW_M   + (size_t)Bc*Nc*256;
constexpr size_t OW_Z2  = OW_Z1  + (size_t)Bc*Nc*128;
constexpr size_t OW_S   = OW_Z2  + (size_t)Bc*Nc*256;

// prep_kernel segment bounds (elements)
constexpr int CV0 = 128*256;            // pool1_w
constexpr int CV1 = CV0 + 256*256;      // pool2_w
constexpr int CV2 = CV1 + 512*256;      // mlp2_w
constexpr int CV3 = CV2 + 512*128;      // sc_w
constexpr int CV4 = CV3 + 128*128;      // w1
constexpr int CV5 = CV4 + 128*32;       // lse1_w padded
constexpr int CV6 = CV5 + 128*32;       // lse2_w padded
constexpr int CVTOT = CV6 + 512;        // + zero ST[0..511]

__global__ void prep_kernel(const float* __restrict__ p1w,
                            const float* __restrict__ p2w,
                            const float* __restrict__ m2w,
                            const float* __restrict__ scw,
                            const float* __restrict__ w1,
                            const float* __restrict__ l1w,
                            const float* __restrict__ l2w,
                            short* __restrict__ W16,
                            float* __restrict__ ST)
{
    int i = blockIdx.x * 256 + threadIdx.x;
    if (i < CV0) { W16[OW_P1W + i] = f2bf(p1w[i]); return; }
    if (i < CV1) { int k = i - CV0; W16[OW_P2W + k] = f2bf(p2w[k]); return; }
    if (i < CV2) { int k = i - CV1; W16[OW_M2W + k] = f2bf(m2w[k]); return; }
    if (i < CV3) { int k = i - CV2; W16[OW_SCW + k] = f2bf(scw[k]); return; }
    if (i < CV4) { int k = i - CV3; W16[OW_W1  + k] = f2bf(w1[k]); return; }
    if (i < CV5) { int k = i - CV4; int o = k >> 5, c = k & 31;
                   W16[OW_L1W + k] = (c < 10) ? f2bf(l1w[o*10+c]) : (short)0; return; }
    if (i < CV6) { int k = i - CV5; int o = k >> 5, c = k & 31;
                   W16[OW_L2W + k] = (c < 10) ? f2bf(l2w[o*10+c]) : (short)0; return; }
    { int k = i - CV6; if (k < 512) ST[k] = 0.f; }
}

// features f32 [b][128][N] -> FB bf16 [b][N][128]
__global__ void feat_t_kernel(const float* __restrict__ in, short* __restrict__ out) {
    int tid  = threadIdx.x;
    int lane = tid & 63, wave = tid >> 6;
    int bb = blockIdx.x / (Nc / 64);
    int n  = (blockIdx.x % (Nc / 64)) * 64 + lane;
    #pragma unroll
    for (int cc = 0; cc < 4; cc++) {
        int c0 = (wave + cc * 4) * 8;
        short8 sv;
        #pragma unroll
        for (int i = 0; i < 8; i++)
            sv[i] = f2bf(in[((size_t)bb * 128 + c0 + i) * Nc + n]);
        *(short8*)&out[((size_t)(bb * Nc + n)) * 128 + c0] = sv;
    }
}

// Reduce S (10) and Q upper-tri (55) of geo over all (n,k), per batch.
__launch_bounds__(256)
__global__ void geo_reduce_kernel(const float* __restrict__ coords,
                                  const int* __restrict__ knn_idx,
                                  const float* __restrict__ knn_dist,
                                  float* __restrict__ dst)   // [B][65]
{
    __shared__ float part[4][65];
    const int tid  = threadIdx.x;
    const int b    = blockIdx.y;
    const int base = blockIdx.x * 256 + tid;          // gridDim.x = 256
    const float* cb  = coords   + (size_t)b * Nc * 3;
    const int*   ib  = knn_idx  + (size_t)b * Nc * Kc;
    const float* db  = knn_dist + (size_t)b * Nc * Kc;

    float acc[65];
    #pragma unroll
    for (int i = 0; i < 65; i++) acc[i] = 0.f;

    #pragma unroll
    for (int it = 0; it < 4; it++) {
        int r = base + it * 65536;                    // covers Nc*Kc = 262144
        int n = r >> 4;
        float cx = cb[n*3+0], cy = cb[n*3+1], cz = cb[n*3+2];
        int   j  = ib[r];
        float nx = cb[j*3+0], ny = cb[j*3+1], nz = cb[j*3+2];
        float d  = db[r];
        float g[10] = {cx,cy,cz,nx,ny,nz,cx-nx,cy-ny,cz-nz,d};
        #pragma unroll
        for (int c = 0; c < 10; c++) acc[c] += g[c];
        int idx = 10;
        #pragma unroll
        for (int c = 0; c < 10; c++)
            #pragma unroll
            for (int c2 = c; c2 < 10; c2++) acc[idx++] += g[c] * g[c2];
    }
    #pragma unroll
    for (int i = 0; i < 65; i++) {
        float v = acc[i];
        #pragma unroll
        for (int off = 1; off < 64; off <<= 1) v += __shfl_xor(v, off);
        acc[i] = v;
    }
    int lane = tid & 63, wave = tid >> 6;
    if (lane == 0) {
        #pragma unroll
        for (int i = 0; i < 65; i++) part[wave][i] = acc[i];
    }
    __syncthreads();
    if (tid < 65) {
        float s = part[0][tid] + part[1][tid] + part[2][tid] + part[3][tid];
        atomicAdd(&dst[b * 65 + tid], s);
    }
}

// Closed-form geo-GN params: for (stage s, batch b, channel o):
//   sum_y = NK*bias + w.S ; sum_y2 = NK*b^2 + 2b(w.S) + w^T Q w
//   group (8ch) mean/var -> pscale = iv*gw, pshift = (bias-mu)*pscale + gb.
// One block, 512 threads = (s,b,o).
__launch_bounds__(512)
__global__ void lse_param_kernel(const float* __restrict__ geoS,  // [B][65]
                                 const float* __restrict__ l1w,
                                 const float* __restrict__ l1b,
                                 const float* __restrict__ l1gw,
                                 const float* __restrict__ l1gb,
                                 const float* __restrict__ l2w,
                                 const float* __restrict__ l2b,
                                 const float* __restrict__ l2gw,
                                 const float* __restrict__ l2gb,
                                 float* __restrict__ lp)          // ST+512
{
    __shared__ float osum[512], osq[512];
    const int tid = threadIdx.x;
    const int s = tid >> 8, r = tid & 255, b = r >> 7, o = r & 127;
    const float* wf = s ? l2w : l1w;
    const float* bf = s ? l2b : l1b;
    const float* gwf = s ? l2gw : l1gw;
    const float* gbf = s ? l2gb : l1gb;
    const float NK = (float)(Nc * Kc);
    const float* S = geoS + b * 65;

    float w[10];
    #pragma unroll
    for (int c = 0; c < 10; c++) w[c] = wf[o * 10 + c];
    float wS = 0.f;
    #pragma unroll
    for (int c = 0; c < 10; c++) wS += w[c] * S[c];
    float q = 0.f;
    {
        int idx = 10;
        #pragma unroll
        for (int c = 0; c < 10; c++)
            #pragma unroll
            for (int c2 = c; c2 < 10; c2++) {
                float t = w[c] * w[c2] * S[idx++];
                q += (c == c2) ? t : 2.f * t;
            }
    }
    float bo = bf[o];
    osum[tid] = NK * bo + wS;
    osq[tid]  = NK * bo * bo + 2.f * bo * wS + q;
    __syncthreads();
    int gb0 = tid & ~7;
    float gs = 0.f, gq = 0.f;
    #pragma unroll
    for (int i = 0; i < 8; i++) { gs += osum[gb0 + i]; gq += osq[gb0 + i]; }
    float cnt  = 8.f * NK;
    float mean = gs / cnt;
    float var  = gq / cnt - mean * mean;
    float iv   = rsqrtf(var + EPSc);
    float psc  = iv * gwf[o];
    float psh  = (bo - mean) * psc + gbf[o];
    lp[s * 512 + b * 256 + o]       = psc;
    lp[s * 512 + b * 256 + 128 + o] = psh;
}

// GEMM: out[b][n][o] = sum_c W[o][c] * X[b][n][c] + bias[o]   (point-major)
// MODE 3: final — B normalized in staging (pool2 GN+relu), epilogue
//         v + GN(sbuf) -> leaky 0.01 -> f32 [b][o][n].
// MODE 4: merged sc(512, raw+stats)/mlp1(128, leaky0.2) by mo tile.
// BK=64 (2 x 32-K MFMA slices per staging pass), stride 68.
template<int CIN, int COUT, int GROUP_CH, int MODE>
__launch_bounds__(256)
__global__ void gemm_conv(const short* __restrict__ wA,   // [COUT][CIN] bf16
                          const short* __restrict__ xB,   // [b][N][CIN] bf16
                          const float* __restrict__ bias,
                          short* __restrict__ outb,
                          float* __restrict__ outf,
                          float* __restrict__ stats,
                          const short* __restrict__ sbuf, // [b][N][512] bf16
                          const float* __restrict__ st_sc,
                          const float* __restrict__ gw,
                          const float* __restrict__ gb,
                          float sc_cnt,
                          const float* __restrict__ bst,  // MODE 3: pool2 stats
                          const float* __restrict__ bgw,
                          const float* __restrict__ bgb,
                          float bcnt,
                          const float* __restrict__ bias2, // MODE 4: mlp1 bias
                          short* __restrict__ outb2)       // MODE 4: X1 out
{
    __shared__ short Abuf[128 * 68];
    __shared__ short Bbuf[128 * 68];
    __shared__ float sstat[32];
    __shared__ float smean[4], sinv[4];
    __shared__ float bsc[256], bsh[256];

    const int tid  = threadIdx.x;
    const int n0   = blockIdx.x * 128;
    const int mo   = blockIdx.y * 128;
    const int b    = blockIdx.z;
    const int lane = tid & 63;
    const int wave = tid >> 6;
    const int wm   = (wave >> 1) * 64;
    const int wn   = (wave & 1) * 64;
    const int l15  = lane & 15;
    const int quad = lane >> 4;
    const bool sc_tile = (MODE == 4) && (mo < 512);

    if constexpr (MODE == 2 || MODE == 4) { if (tid < 32) sstat[tid] = 0.f; }
    if constexpr (MODE == 3) {
        if (tid < 4) {
            int g = (mo >> 5) + tid;
            float s0 = st_sc[(b * 16 + g) * 2 + 0];
            float s1 = st_sc[(b * 16 + g) * 2 + 1];
            float mean = s0 / sc_cnt;
            float var  = s1 / sc_cnt - mean * mean;
            smean[tid] = mean;
            sinv[tid]  = rsqrtf(var + EPSc);
        }
        if (tid < CIN) {   // pool2 GN: 256 ch, 16 ch/group
            int g = tid >> 4;
            float s0 = bst[(b * 16 + g) * 2 + 0];
            float s1 = bst[(b * 16 + g) * 2 + 1];
            float mean = s0 / bcnt;
            float var  = s1 / bcnt - mean * mean;
            float inv  = rsqrtf(var + EPSc);
            float sc_  = inv * bgw[tid];
            bsc[tid] = sc_;
            bsh[tid] = bgb[tid] - mean * sc_;
        }
    }

    floatx4 acc[4][4];
    #pragma unroll
    for (int mi = 0; mi < 4; mi++)
        #pragma unroll
        for (int ni = 0; ni < 4; ni++)
            acc[mi][ni] = (floatx4){0.f, 0.f, 0.f, 0.f};

    const short* wAr = wA + (size_t)mo * CIN;
    const short* xBr = xB + (size_t)b * Nc * CIN + (size_t)n0 * CIN;

    for (int c0 = 0; c0 < CIN; c0 += 64) {
        __syncthreads();
        #pragma unroll
        for (int s = 0; s < 4; s++) {
            int e = tid + s * 256;
            int r = e >> 3, q = e & 7;
            *(short8*)&Abuf[r * 68 + q * 8] =
                *(const short8*)(wAr + (size_t)r * CIN + c0 + q * 8);
            short8 v = *(const short8*)(xBr + (size_t)r * CIN + c0 + q * 8);
            if constexpr (MODE == 3) {
                #pragma unroll
                for (int i = 0; i < 8; i++) {
                    int ch = c0 + q * 8 + i;
                    float t = bf2f(v[i]) * bsc[ch] + bsh[ch];
                    v[i] = f2bf(t > 0.f ? t : 0.f);
                }
            }
            *(short8*)&Bbuf[r * 68 + q * 8] = v;
        }
        __syncthreads();

        #pragma unroll
        for (int kk = 0; kk < 2; kk++) {
            short8 af[4], bfr[4];
            #pragma unroll
            for (int mi = 0; mi < 4; mi++)
                af[mi] = *(short8*)&Abuf[(wm + mi * 16 + l15) * 68 + kk * 32 + quad * 8];
            #pragma unroll
            for (int ni = 0; ni < 4; ni++)
                bfr[ni] = *(short8*)&Bbuf[(wn + ni * 16 + l15) * 68 + kk * 32 + quad * 8];
            #pragma unroll
            for (int mi = 0; mi < 4; mi++)
                #pragma unroll
                for (int ni = 0; ni < 4; ni++)
                    acc[mi][ni] = __builtin_amdgcn_mfma_f32_16x16x32_bf16(
                        af[mi], bfr[ni], acc[mi][ni], 0, 0, 0);
        }
    }

    // D row(o) = mo+wm+mi*16+quad*4+r, col(n) = n0+wn+ni*16+l15
    #pragma unroll
    for (int mi = 0; mi < 4; mi++) {
        int rowl = wm + mi * 16 + quad * 4;
        float b4[4], gw4[4], gb4[4];
        #pragma unroll
        for (int r = 0; r < 4; r++) {
            if constexpr (MODE == 4) {
                b4[r] = sc_tile ? bias[mo + rowl + r] : bias2[mo - 512 + rowl + r];
            } else {
                b4[r] = bias[mo + rowl + r];
            }
            if constexpr (MODE == 3) {
                gw4[r] = gw[mo + rowl + r];
                gb4[r] = gb[mo + rowl + r];
            }
        }
        float gs = 0.f, gq = 0.f;
        #pragma unroll
        for (int ni = 0; ni < 4; ni++) {
            int col = n0 + wn + ni * 16 + l15;
            if constexpr (MODE == 3) {
                short4v s4 = *(const short4v*)&sbuf[((size_t)(b * Nc + col)) * 512 + mo + rowl];
                int gl = rowl >> 5;
                #pragma unroll
                for (int r = 0; r < 4; r++) {
                    float v = acc[mi][ni][r] + b4[r];
                    float s = bf2f(s4[r]);
                    float sn = (s - smean[gl]) * sinv[gl] * gw4[r] + gb4[r];
                    float o = v + sn;
                    o = o > 0.f ? o : 0.01f * o;
                    outf[((size_t)b * COUT + mo + rowl + r) * Nc + col] = o;
                }
            } else if constexpr (MODE == 4) {
                short4v sv;
                #pragma unroll
                for (int r = 0; r < 4; r++) {
                    float v = acc[mi][ni][r] + b4[r];
                    if (sc_tile) { gs += v; gq += v * v; }
                    else v = v > 0.f ? v : 0.2f * v;
                    sv[r] = f2bf(v);
                }
                if (sc_tile)
                    *(short4v*)&outb[((size_t)(b * Nc + col)) * 512 + mo + rowl] = sv;
                else
                    *(short4v*)&outb2[((size_t)(b * Nc + col)) * 128 + mo - 512 + rowl] = sv;
            } else {
                short4v sv;
                #pragma unroll
                for (int r = 0; r < 4; r++) {
                    float v = acc[mi][ni][r] + b4[r];
                    if constexpr (MODE == 1) v = v > 0.f ? v : 0.2f * v;
                    if constexpr (MODE == 2) { gs += v; gq += v * v; }
                    sv[r] = f2bf(v);
                }
                *(short4v*)&outb[((size_t)(b * Nc + col)) * COUT + mo + rowl] = sv;
            }
        }
        if ((MODE == 2) || (MODE == 4 && sc_tile)) {
            #pragma unroll
            for (int off = 1; off < 16; off <<= 1) {
                gs += __shfl_xor(gs, off);
                gq += __shfl_xor(gq, off);
            }
            if (l15 == 0) {
                int gl = rowl / GROUP_CH;
                atomicAdd(&sstat[gl * 2 + 0], gs);
                atomicAdd(&sstat[gl * 2 + 1], gq);
            }
        }
    }
    if ((MODE == 2) || (MODE == 4 && sc_tile)) {
        __syncthreads();
        constexpr int NG = 128 / GROUP_CH;
        if (tid < 2 * NG) {
            int g0 = mo / GROUP_CH;
            atomicAdd(&stats[b * 32 + (g0 + (tid >> 1)) * 2 + (tid & 1)], sstat[tid]);
        }
    }
}

// Fused LSE + pool: 32-point tile, 512 threads (8 waves), grid 1024 blocks
// = 4 blocks/CU (grid was the occupancy limiter at 64-pt/512 blocks).
//  A) geo conv (MFMA, precomputed GN) + relu + mean_k  -> m_lds[p][0:128]
//     (2 passes x 16 points; Bbuf = 256 cols = 20KB; r11 structure)
//  B) neighbor gather-mean (opt. folded prev-pool GN)  -> m_lds[p][128:256]
//  C) pool GEMM (PCOUT x 32 x 256) from m_lds, A-frags straight from L2,
//     raw bf16 out + group-stats atomics.
// m_lds channel-groups XOR-swizzled (g ^= p&7) -> all LDS phases <=2-way.
// Total static LDS ~39.1KB -> 4 blocks/CU (LDS 4.09, grid 4, VGPR free).
// PCOUT: 128 (pool1, group 8) / 256 (pool2, group 16).
template<int PCOUT, int PGROUP>
__launch_bounds__(512)
__global__ void lse_pool_kernel(const float* __restrict__ coords,
                                const int* __restrict__ knn_idx,
                                const float* __restrict__ knn_dist,
                                const short* __restrict__ xprev, // [b][N][128]
                                const short* __restrict__ wpad,  // [128][32]
                                const float* __restrict__ lp,    // geo GN params
                                const float* __restrict__ xst,   // prev stats or null
                                const float* __restrict__ xgw,
                                const float* __restrict__ xgb,
                                float xcnt,
                                const short* __restrict__ pw,    // [PCOUT][256]
                                const float* __restrict__ pb,    // [PCOUT]
                                float* __restrict__ stats,       // [B][32]
                                short* __restrict__ z)           // [b][N][PCOUT]
{
    __shared__ short Bbuf[256 * 40];        // 20 KB: one 16-pt geo sub-tile
    __shared__ short mld[32 * 256];         // 16 KB: m rows, group-swizzled
    __shared__ int   jl[512];               // [k][p]
    __shared__ float xscs[128], xshs[128];
    __shared__ float sstat[32];

    const int tid = threadIdx.x;
    const int b   = blockIdx.x >> 9;        // Nc/32 = 512 blocks per batch
    const int n0  = (blockIdx.x & 511) * 32;
    const bool norm = (xst != nullptr);
    const int lane = tid & 63, wave = tid >> 6;
    const int l15 = lane & 15, quad = lane >> 4;

    if (tid < 32) sstat[tid] = 0.f;
    if (norm && tid < 128) {                // prev-pool GN fold: 8 ch/group
        int g = tid >> 3;
        float s0 = xst[(b * 16 + g) * 2 + 0];
        float s1 = xst[(b * 16 + g) * 2 + 1];
        float mean = s0 / xcnt;
        float var  = s1 / xcnt - mean * mean;
        float inv  = rsqrtf(var + EPSc);
        float sc_  = inv * xgw[tid];
        xscs[tid] = sc_;
        xshs[tid] = xgb[tid] - mean * sc_;
    }

    // hoisted geo A-frag + GN params (o-tile = wave; 8 waves x 16 = 128 ch)
    short8 af = *(const short8*)(wpad + (wave * 16 + l15) * 32 + quad * 8);
    floatx4 psc = *(const floatx4*)&lp[b * 256 + wave * 16 + quad * 4];
    floatx4 psh = *(const floatx4*)&lp[b * 256 + 128 + wave * 16 + quad * 4];

    const float* cb = coords + (size_t)b * Nc * 3;

    // ---- phase A: geo conv + relu + mean_k -> mld[p][0:128] ----
    #pragma unroll
    for (int pass = 0; pass < 2; pass++) {
        if (tid < 256) {   // build 256 cols (16 points x 16 k): col = tid
            int ptl = tid & 15, k = tid >> 4;
            int p = pass * 16 + ptl;
            int n = n0 + p;
            float cx = cb[n*3+0], cy = cb[n*3+1], cz = cb[n*3+2];
            int   j  = knn_idx[((size_t)b * Nc + n) * Kc + k];
            float nx = cb[j*3+0], ny = cb[j*3+1], nz = cb[j*3+2];
            float d  = knn_dist[((size_t)b * Nc + n) * Kc + k];
            int col = k * 16 + ptl;
            short8 w0, w1, zz;
            w0[0]=f2bf(cx); w0[1]=f2bf(cy); w0[2]=f2bf(cz);
            w0[3]=f2bf(nx); w0[4]=f2bf(ny); w0[5]=f2bf(nz);
            w0[6]=f2bf(cx-nx); w0[7]=f2bf(cy-ny);
            w1[0]=f2bf(cz-nz); w1[1]=f2bf(d);
            #pragma unroll
            for (int i = 2; i < 8; i++) w1[i] = 0;
            #pragma unroll
            for (int i = 0; i < 8; i++) zz[i] = 0;
            *(short8*)&Bbuf[col * 40 + 0]  = w0;
            *(short8*)&Bbuf[col * 40 + 8]  = w1;
            *(short8*)&Bbuf[col * 40 + 16] = zz;
            *(short8*)&Bbuf[col * 40 + 24] = zz;
            jl[k * 32 + p] = j;
        }
        __syncthreads();
        {
            float s4[4] = {0.f, 0.f, 0.f, 0.f};
            #pragma unroll
            for (int nb = 0; nb < 8; nb++) {
                short8 f0 = *(short8*)&Bbuf[((nb*2+0)*16 + l15) * 40 + quad * 8];
                short8 f1 = *(short8*)&Bbuf[((nb*2+1)*16 + l15) * 40 + quad * 8];
                floatx4 a0 = __builtin_amdgcn_mfma_f32_16x16x32_bf16(
                    af, f0, (floatx4){0.f, 0.f, 0.f, 0.f}, 0, 0, 0);
                floatx4 a1 = __builtin_amdgcn_mfma_f32_16x16x32_bf16(
                    af, f1, (floatx4){0.f, 0.f, 0.f, 0.f}, 0, 0, 0);
                #pragma unroll
                for (int r = 0; r < 4; r++) {
                    float v0 = a0[r] * psc[r] + psh[r];
                    float v1 = a1[r] * psc[r] + psh[r];
                    s4[r] += (v0 > 0.f ? v0 : 0.f) + (v1 > 0.f ? v1 : 0.f);
                }
            }
            // D col = point l15, rows o = wave*16 + quad*4 + r
            int p = pass * 16 + l15;
            int g = wave * 2 + (quad >> 1);          // ch group (0..15)
            short4v sv;
            #pragma unroll
            for (int r = 0; r < 4; r++) sv[r] = f2bf(s4[r] * (1.f / 16.f));
            *(short4v*)&mld[p * 256 + ((g ^ (p & 7)) << 3) + (quad & 1) * 4] = sv;
        }
        __syncthreads();
    }

    // ---- phase B: gather-mean -> mld[p][128:256] (jl complete) ----
    {
        const int tp = tid >> 4, cs = tid & 15;     // tp in [0,32) = point
        float sc8[8], sh8[8];
        if (norm) {
            #pragma unroll
            for (int i = 0; i < 8; i++) { sc8[i] = xscs[cs*8+i]; sh8[i] = xshs[cs*8+i]; }
        }
        float acc8[8];
        #pragma unroll
        for (int i = 0; i < 8; i++) acc8[i] = 0.f;
        #pragma unroll
        for (int k = 0; k < 16; k++) {
            int j = jl[k * 32 + tp];
            short8 v = *(const short8*)&xprev[((size_t)(b * Nc + j)) * 128 + cs * 8];
            if (norm) {
                #pragma unroll
                for (int i = 0; i < 8; i++) {
                    float t = bf2f(v[i]) * sc8[i] + sh8[i];
                    acc8[i] += t > 0.f ? t : 0.f;
                }
            } else {
                #pragma unroll
                for (int i = 0; i < 8; i++) acc8[i] += bf2f(v[i]);
            }
        }
        short8 sv;
        #pragma unroll
        for (int i = 0; i < 8; i++) sv[i] = f2bf(acc8[i] * (1.f / 16.f));
        int g = 16 + cs;
        *(short8*)&mld[tp * 256 + ((g ^ (tp & 7)) << 3)] = sv;
    }
    __syncthreads();

    // ---- phase C: pool GEMM (PCOUT x 32pts x 256ch) ----
    constexpr int NOT = PCOUT / 128;               // o-tiles per wave (1 or 2)
    #pragma unroll
    for (int oi = 0; oi < NOT; oi++) {
        const int ot = wave + oi * 8;
        short8 afk[8];
        #pragma unroll
        for (int ks = 0; ks < 8; ks++)
            afk[ks] = *(const short8*)(pw + ((size_t)(ot * 16 + l15)) * 256 + ks * 32 + quad * 8);
        floatx4 acc[2];
        #pragma unroll
        for (int nt = 0; nt < 2; nt++) acc[nt] = (floatx4){0.f, 0.f, 0.f, 0.f};
        #pragma unroll
        for (int ks = 0; ks < 8; ks++) {
            #pragma unroll
            for (int nt = 0; nt < 2; nt++) {
                int p = nt * 16 + l15;
                int g = ks * 4 + quad;
                short8 bfr = *(short8*)&mld[p * 256 + ((g ^ (p & 7)) << 3)];
                acc[nt] = __builtin_amdgcn_mfma_f32_16x16x32_bf16(
                    afk[ks], bfr, acc[nt], 0, 0, 0);
            }
        }
        floatx4 b4 = *(const floatx4*)&pb[ot * 16 + quad * 4];
        float gs = 0.f, gq = 0.f;
        #pragma unroll
        for (int nt = 0; nt < 2; nt++) {
            int col = n0 + nt * 16 + l15;
            short4v sv;
            #pragma unroll
            for (int r = 0; r < 4; r++) {
                float v = acc[nt][r] + b4[r];
                gs += v; gq += v * v;
                sv[r] = f2bf(v);
            }
            *(short4v*)&z[((size_t)(b * Nc + col)) * PCOUT + ot * 16 + quad * 4] = sv;
        }
        #pragma unroll
        for (int off = 1; off < 16; off <<= 1) {
            gs += __shfl_xor(gs, off);
            gq += __shfl_xor(gq, off);
        }
        if (l15 == 0) {
            int gl = (ot * 16 + quad * 4) / PGROUP;
            atomicAdd(&sstat[gl * 2 + 0], gs);
            atomicAdd(&sstat[gl * 2 + 1], gq);
        }
    }
    __syncthreads();
    if (tid < 32) atomicAdd(&stats[b * 32 + tid], sstat[tid]);
}

extern "C" void kernel_launch(void* const* d_in, const int* in_sizes, int n_in,
                              void* d_out, int out_size, void* d_ws, size_t ws_size,
                              hipStream_t stream)
{
    const float* coords   = (const float*)d_in[0];
    const float* features = (const float*)d_in[1];
    const float* knn_dist = (const float*)d_in[2];
    const int*   knn_idx  = (const int*)  d_in[3];
    const float* w1       = (const float*)d_in[4];
    const float* b1       = (const float*)d_in[5];
    const float* lse1_w   = (const float*)d_in[6];
    const float* lse1_b   = (const float*)d_in[7];
    const float* lse1_gw  = (const float*)d_in[8];
    const float* lse1_gb  = (const float*)d_in[9];
    const float* pool1_w  = (const float*)d_in[10];
    const float* pool1_b  = (const float*)d_in[11];
    const float* pool1_gw = (const float*)d_in[12];
    const float* pool1_gb = (const float*)d_in[13];
    const float* lse2_w   = (const float*)d_in[14];
    const float* lse2_b   = (const float*)d_in[15];
    const float* lse2_gw  = (const float*)d_in[16];
    const float* lse2_gb  = (const float*)d_in[17];
    const float* pool2_w  = (const float*)d_in[18];
    const float* pool2_b  = (const float*)d_in[19];
    const float* pool2_gw = (const float*)d_in[20];
    const float* pool2_gb = (const float*)d_in[21];
    const float* mlp2_w   = (const float*)d_in[22];
    const float* mlp2_b   = (const float*)d_in[23];
    const float* sc_w     = (const float*)d_in[24];
    const float* sc_b     = (const float*)d_in[25];
    const float* sc_gw    = (const float*)d_in[26];
    const float* sc_gb    = (const float*)d_in[27];
    (void)in_sizes; (void)n_in; (void)out_size; (void)ws_size;

    float* ST = (float*)d_ws;           // 2048 floats
    float* ST_SC  = ST + 0;
    float* ST_P1  = ST + 64;
    float* ST_P2  = ST + 128;
    float* ST_GEO = ST + 256;           // B x 65
    float* ST_LP  = ST + 512;           // [stage][b][{psc,psh}x128]
    short* W16 = (short*)(ST + 2048);
    short* P1Wb = W16 + OW_P1W;
    short* P2Wb = W16 + OW_P2W;
    short* M2Wb = W16 + OW_M2W;
    short* SCWb = W16 + OW_SCW;         // rows 0..511 sc, 512..639 w1
    short* L1Wb = W16 + OW_L1W;
    short* L2Wb = W16 + OW_L2W;
    short* FB   = W16 + OW_FB;
    short* X1B  = W16 + OW_X1;
    short* Z1   = W16 + OW_Z1;
    short* Z2   = W16 + OW_Z2;
    short* SB   = W16 + OW_S;
    float* out  = (float*)d_out;

    prep_kernel<<<(CVTOT + 255) / 256, 256, 0, stream>>>(
        pool1_w, pool2_w, mlp2_w, sc_w, w1, lse1_w, lse2_w, W16, ST);
    feat_t_kernel<<<Bc * Nc / 64, 256, 0, stream>>>(features, FB);
    geo_reduce_kernel<<<dim3(256, Bc), 256, 0, stream>>>(
        coords, knn_idx, knn_dist, ST_GEO);
    lse_param_kernel<<<1, 512, 0, stream>>>(
        ST_GEO, lse1_w, lse1_b, lse1_gw, lse1_gb,
        lse2_w, lse2_b, lse2_gw, lse2_gb, ST_LP);

    // merged sc (512, raw bf16 + stats, group=32ch) + mlp1 (128, leaky 0.2)
    gemm_conv<128,640,32,4><<<dim3(Nc/128, 5, Bc), 256, 0, stream>>>(
        SCWb, FB, sc_b, SB, nullptr, ST_SC, nullptr, nullptr, nullptr, nullptr, 0.f,
        nullptr, nullptr, nullptr, 0.f, b1, X1B);
    // fused lse1 + pool1 (128 out, group 8): X1B gather raw, stats -> ST_P1
    lse_pool_kernel<128,8><<<Bc * Nc / 32, 512, 0, stream>>>(
        coords, knn_idx, knn_dist, X1B, L1Wb, ST_LP,
        nullptr, nullptr, nullptr, 0.f,
        P1Wb, pool1_b, ST_P1, Z1);
    // fused lse2 + pool2 (256 out, group 16): Z1 gather + pool1-GN fold,
    // stats -> ST_P2
    lse_pool_kernel<256,16><<<Bc * Nc / 32, 512, 0, stream>>>(
        coords, knn_idx, knn_dist, Z1, L2Wb, ST_LP + 512,
        ST_P1, pool1_gw, pool1_gb, (float)(8 * Nc),
        P2Wb, pool2_b, ST_P2, Z2);
    // final: mlp2(GN+relu(Z2) folded into staging) + GN(S) -> leaky 0.01 -> f32
    gemm_conv<256,512,32,3><<<dim3(Nc/128, 4, Bc), 256, 0, stream>>>(
        M2Wb, Z2, mlp2_b, nullptr, out, nullptr, SB, ST_SC, sc_gw, sc_gb,
        (float)(32 * Nc), ST_P2, pool2_gw, pool2_gb, (float)(16 * Nc),
        nullptr, nullptr);
}

// Round 8
// 285.611 us; speedup vs baseline: 1.0394x; 1.0263x over previous
//
#include <hip/hip_runtime.h>

// LocalFeatureAggregation — bf16-MFMA pipeline, point-major activations.
// B=2, N=16384, K=16, D_IN=128, D_OUT=256, GROUPS=16.
//
// Round-14:
//  - lse_pool reverted to the r11 64-pt structure (measured 42.0us; the
//    r12 LDS-diet and r13 grid-split occupancy raises were both null on
//    duration -> kernel is not TLP-starved; 32-pt tile doubled per-block
//    fixed costs and mildly regressed).
//  - prep + feat_t merged into one dispatch (independent pure writes; -1
//    launch). geo_reduce NOT merged: its ST_GEO atomics need the ST zeroing
//    from the prior dispatch (stream order) — merging would race.

constexpr int Bc = 2;
constexpr int Nc = 16384;
constexpr int Kc = 16;
constexpr float EPSc = 1e-6f;

typedef __attribute__((ext_vector_type(8))) short short8;
typedef __attribute__((ext_vector_type(4))) short short4v;
typedef __attribute__((ext_vector_type(4))) float floatx4;

__device__ inline short f2bf(float x) {
    union { float f; unsigned u; } v; v.f = x;
    unsigned r = v.u + 0x7fffu + ((v.u >> 16) & 1u);
    return (short)(r >> 16);
}
__device__ inline float bf2f(short s) {
    union { unsigned u; float f; } v;
    v.u = ((unsigned)(unsigned short)s) << 16;
    return v.f;
}

// ---- workspace layout ----
// f32 ST[2048]: ST_SC=0, ST_P1=64, ST_P2=128, ST_GEO=256 (B x 65),
//               ST_LP=512: [stage][b][{psc,psh}x128] = 2*512 floats (512..1535)
// then bf16 (short) region, offsets in shorts:
constexpr size_t OW_P1W = 0;                        // 128*256
constexpr size_t OW_P2W = OW_P1W + 128*256;         // 256*256
constexpr size_t OW_M2W = OW_P2W + 256*256;         // 512*256
constexpr size_t OW_SCW = OW_M2W + 512*256;         // 512*128 (sc rows 0..511)
constexpr size_t OW_W1  = OW_SCW + 512*128;         // 128*128 (rows 512..639)
constexpr size_t OW_L1W = OW_W1  + 128*128;         // 128*32 (K padded)
constexpr size_t OW_L2W = OW_L1W + 128*32;          // 128*32
constexpr size_t OW_FB  = OW_L2W + 128*32;          // B*N*128
constexpr size_t OW_X1  = OW_FB  + (size_t)Bc*Nc*128;
constexpr size_t OW_M   = OW_X1  + (size_t)Bc*Nc*128;
constexpr size_t OW_Z1  = OW_M   + (size_t)Bc*Nc*256;
constexpr size_t OW_Z2  = OW_Z1  + (size_t)Bc*Nc*128;
constexpr size_t OW_S   = OW_Z2  + (size_t)Bc*Nc*256;

// prep segment bounds (elements)
constexpr int CV0 = 128*256;            // pool1_w
constexpr int CV1 = CV0 + 256*256;      // pool2_w
constexpr int CV2 = CV1 + 512*256;      // mlp2_w
constexpr int CV3 = CV2 + 512*128;      // sc_w
constexpr int CV4 = CV3 + 128*128;      // w1
constexpr int CV5 = CV4 + 128*32;       // lse1_w padded
constexpr int CV6 = CV5 + 128*32;       // lse2_w padded
constexpr int CVTOT = CV6 + 512;        // + zero ST[0..511]
constexpr int PREP_BLKS = (CVTOT + 255) / 256;
constexpr int FEAT_BLKS = Bc * Nc / 64;

// Merged: weight-convert/zero (blocks 0..PREP_BLKS) + features transpose
// f32 [b][128][N] -> FB bf16 [b][N][128] (blocks PREP_BLKS..+FEAT_BLKS).
__launch_bounds__(256)
__global__ void prep_feat_kernel(const float* __restrict__ p1w,
                                 const float* __restrict__ p2w,
                                 const float* __restrict__ m2w,
                                 const float* __restrict__ scw,
                                 const float* __restrict__ w1,
                                 const float* __restrict__ l1w,
                                 const float* __restrict__ l2w,
                                 short* __restrict__ W16,
                                 float* __restrict__ ST,
                                 const float* __restrict__ fin,
                                 short* __restrict__ fout)
{
    const int blk = blockIdx.x;
    const int tid = threadIdx.x;
    if (blk < PREP_BLKS) {
        int i = blk * 256 + tid;
        if (i < CV0) { W16[OW_P1W + i] = f2bf(p1w[i]); return; }
        if (i < CV1) { int k = i - CV0; W16[OW_P2W + k] = f2bf(p2w[k]); return; }
        if (i < CV2) { int k = i - CV1; W16[OW_M2W + k] = f2bf(m2w[k]); return; }
        if (i < CV3) { int k = i - CV2; W16[OW_SCW + k] = f2bf(scw[k]); return; }
        if (i < CV4) { int k = i - CV3; W16[OW_W1  + k] = f2bf(w1[k]); return; }
        if (i < CV5) { int k = i - CV4; int o = k >> 5, c = k & 31;
                       W16[OW_L1W + k] = (c < 10) ? f2bf(l1w[o*10+c]) : (short)0; return; }
        if (i < CV6) { int k = i - CV5; int o = k >> 5, c = k & 31;
                       W16[OW_L2W + k] = (c < 10) ? f2bf(l2w[o*10+c]) : (short)0; return; }
        { int k = i - CV6; if (k < 512) ST[k] = 0.f; }
        return;
    }
    // feat_t part
    const int fb  = blk - PREP_BLKS;
    int lane = tid & 63, wave = tid >> 6;
    int bb = fb / (Nc / 64);
    int n  = (fb % (Nc / 64)) * 64 + lane;
    #pragma unroll
    for (int cc = 0; cc < 4; cc++) {
        int c0 = (wave + cc * 4) * 8;
        short8 sv;
        #pragma unroll
        for (int i = 0; i < 8; i++)
            sv[i] = f2bf(fin[((size_t)bb * 128 + c0 + i) * Nc + n]);
        *(short8*)&fout[((size_t)(bb * Nc + n)) * 128 + c0] = sv;
    }
}

// Reduce S (10) and Q upper-tri (55) of geo over all (n,k), per batch.
__launch_bounds__(256)
__global__ void geo_reduce_kernel(const float* __restrict__ coords,
                                  const int* __restrict__ knn_idx,
                                  const float* __restrict__ knn_dist,
                                  float* __restrict__ dst)   // [B][65]
{
    __shared__ float part[4][65];
    const int tid  = threadIdx.x;
    const int b    = blockIdx.y;
    const int base = blockIdx.x * 256 + tid;          // gridDim.x = 256
    const float* cb  = coords   + (size_t)b * Nc * 3;
    const int*   ib  = knn_idx  + (size_t)b * Nc * Kc;
    const float* db  = knn_dist + (size_t)b * Nc * Kc;

    float acc[65];
    #pragma unroll
    for (int i = 0; i < 65; i++) acc[i] = 0.f;

    #pragma unroll
    for (int it = 0; it < 4; it++) {
        int r = base + it * 65536;                    // covers Nc*Kc = 262144
        int n = r >> 4;
        float cx = cb[n*3+0], cy = cb[n*3+1], cz = cb[n*3+2];
        int   j  = ib[r];
        float nx = cb[j*3+0], ny = cb[j*3+1], nz = cb[j*3+2];
        float d  = db[r];
        float g[10] = {cx,cy,cz,nx,ny,nz,cx-nx,cy-ny,cz-nz,d};
        #pragma unroll
        for (int c = 0; c < 10; c++) acc[c] += g[c];
        int idx = 10;
        #pragma unroll
        for (int c = 0; c < 10; c++)
            #pragma unroll
            for (int c2 = c; c2 < 10; c2++) acc[idx++] += g[c] * g[c2];
    }
    #pragma unroll
    for (int i = 0; i < 65; i++) {
        float v = acc[i];
        #pragma unroll
        for (int off = 1; off < 64; off <<= 1) v += __shfl_xor(v, off);
        acc[i] = v;
    }
    int lane = tid & 63, wave = tid >> 6;
    if (lane == 0) {
        #pragma unroll
        for (int i = 0; i < 65; i++) part[wave][i] = acc[i];
    }
    __syncthreads();
    if (tid < 65) {
        float s = part[0][tid] + part[1][tid] + part[2][tid] + part[3][tid];
        atomicAdd(&dst[b * 65 + tid], s);
    }
}

// Closed-form geo-GN params: for (stage s, batch b, channel o):
//   sum_y = NK*bias + w.S ; sum_y2 = NK*b^2 + 2b(w.S) + w^T Q w
//   group (8ch) mean/var -> pscale = iv*gw, pshift = (bias-mu)*pscale + gb.
// One block, 512 threads = (s,b,o).
__launch_bounds__(512)
__global__ void lse_param_kernel(const float* __restrict__ geoS,  // [B][65]
                                 const float* __restrict__ l1w,
                                 const float* __restrict__ l1b,
                                 const float* __restrict__ l1gw,
                                 const float* __restrict__ l1gb,
                                 const float* __restrict__ l2w,
                                 const float* __restrict__ l2b,
                                 const float* __restrict__ l2gw,
                                 const float* __restrict__ l2gb,
                                 float* __restrict__ lp)          // ST+512
{
    __shared__ float osum[512], osq[512];
    const int tid = threadIdx.x;
    const int s = tid >> 8, r = tid & 255, b = r >> 7, o = r & 127;
    const float* wf = s ? l2w : l1w;
    const float* bf = s ? l2b : l1b;
    const float* gwf = s ? l2gw : l1gw;
    const float* gbf = s ? l2gb : l1gb;
    const float NK = (float)(Nc * Kc);
    const float* S = geoS + b * 65;

    float w[10];
    #pragma unroll
    for (int c = 0; c < 10; c++) w[c] = wf[o * 10 + c];
    float wS = 0.f;
    #pragma unroll
    for (int c = 0; c < 10; c++) wS += w[c] * S[c];
    float q = 0.f;
    {
        int idx = 10;
        #pragma unroll
        for (int c = 0; c < 10; c++)
            #pragma unroll
            for (int c2 = c; c2 < 10; c2++) {
                float t = w[c] * w[c2] * S[idx++];
                q += (c == c2) ? t : 2.f * t;
            }
    }
    float bo = bf[o];
    osum[tid] = NK * bo + wS;
    osq[tid]  = NK * bo * bo + 2.f * bo * wS + q;
    __syncthreads();
    int gb0 = tid & ~7;
    float gs = 0.f, gq = 0.f;
    #pragma unroll
    for (int i = 0; i < 8; i++) { gs += osum[gb0 + i]; gq += osq[gb0 + i]; }
    float cnt  = 8.f * NK;
    float mean = gs / cnt;
    float var  = gq / cnt - mean * mean;
    float iv   = rsqrtf(var + EPSc);
    float psc  = iv * gwf[o];
    float psh  = (bo - mean) * psc + gbf[o];
    lp[s * 512 + b * 256 + o]       = psc;
    lp[s * 512 + b * 256 + 128 + o] = psh;
}

// GEMM: out[b][n][o] = sum_c W[o][c] * X[b][n][c] + bias[o]   (point-major)
// MODE 3: final — B normalized in staging (pool2 GN+relu), epilogue
//         v + GN(sbuf) -> leaky 0.01 -> f32 [b][o][n].
// MODE 4: merged sc(512, raw+stats)/mlp1(128, leaky0.2) by mo tile.
// BK=64 (2 x 32-K MFMA slices per staging pass), stride 68.
template<int CIN, int COUT, int GROUP_CH, int MODE>
__launch_bounds__(256)
__global__ void gemm_conv(const short* __restrict__ wA,   // [COUT][CIN] bf16
                          const short* __restrict__ xB,   // [b][N][CIN] bf16
                          const float* __restrict__ bias,
                          short* __restrict__ outb,
                          float* __restrict__ outf,
                          float* __restrict__ stats,
                          const short* __restrict__ sbuf, // [b][N][512] bf16
                          const float* __restrict__ st_sc,
                          const float* __restrict__ gw,
                          const float* __restrict__ gb,
                          float sc_cnt,
                          const float* __restrict__ bst,  // MODE 3: pool2 stats
                          const float* __restrict__ bgw,
                          const float* __restrict__ bgb,
                          float bcnt,
                          const float* __restrict__ bias2, // MODE 4: mlp1 bias
                          short* __restrict__ outb2)       // MODE 4: X1 out
{
    __shared__ short Abuf[128 * 68];
    __shared__ short Bbuf[128 * 68];
    __shared__ float sstat[32];
    __shared__ float smean[4], sinv[4];
    __shared__ float bsc[256], bsh[256];

    const int tid  = threadIdx.x;
    const int n0   = blockIdx.x * 128;
    const int mo   = blockIdx.y * 128;
    const int b    = blockIdx.z;
    const int lane = tid & 63;
    const int wave = tid >> 6;
    const int wm   = (wave >> 1) * 64;
    const int wn   = (wave & 1) * 64;
    const int l15  = lane & 15;
    const int quad = lane >> 4;
    const bool sc_tile = (MODE == 4) && (mo < 512);

    if constexpr (MODE == 2 || MODE == 4) { if (tid < 32) sstat[tid] = 0.f; }
    if constexpr (MODE == 3) {
        if (tid < 4) {
            int g = (mo >> 5) + tid;
            float s0 = st_sc[(b * 16 + g) * 2 + 0];
            float s1 = st_sc[(b * 16 + g) * 2 + 1];
            float mean = s0 / sc_cnt;
            float var  = s1 / sc_cnt - mean * mean;
            smean[tid] = mean;
            sinv[tid]  = rsqrtf(var + EPSc);
        }
        if (tid < CIN) {   // pool2 GN: 256 ch, 16 ch/group
            int g = tid >> 4;
            float s0 = bst[(b * 16 + g) * 2 + 0];
            float s1 = bst[(b * 16 + g) * 2 + 1];
            float mean = s0 / bcnt;
            float var  = s1 / bcnt - mean * mean;
            float inv  = rsqrtf(var + EPSc);
            float sc_  = inv * bgw[tid];
            bsc[tid] = sc_;
            bsh[tid] = bgb[tid] - mean * sc_;
        }
    }

    floatx4 acc[4][4];
    #pragma unroll
    for (int mi = 0; mi < 4; mi++)
        #pragma unroll
        for (int ni = 0; ni < 4; ni++)
            acc[mi][ni] = (floatx4){0.f, 0.f, 0.f, 0.f};

    const short* wAr = wA + (size_t)mo * CIN;
    const short* xBr = xB + (size_t)b * Nc * CIN + (size_t)n0 * CIN;

    for (int c0 = 0; c0 < CIN; c0 += 64) {
        __syncthreads();
        #pragma unroll
        for (int s = 0; s < 4; s++) {
            int e = tid + s * 256;
            int r = e >> 3, q = e & 7;
            *(short8*)&Abuf[r * 68 + q * 8] =
                *(const short8*)(wAr + (size_t)r * CIN + c0 + q * 8);
            short8 v = *(const short8*)(xBr + (size_t)r * CIN + c0 + q * 8);
            if constexpr (MODE == 3) {
                #pragma unroll
                for (int i = 0; i < 8; i++) {
                    int ch = c0 + q * 8 + i;
                    float t = bf2f(v[i]) * bsc[ch] + bsh[ch];
                    v[i] = f2bf(t > 0.f ? t : 0.f);
                }
            }
            *(short8*)&Bbuf[r * 68 + q * 8] = v;
        }
        __syncthreads();

        #pragma unroll
        for (int kk = 0; kk < 2; kk++) {
            short8 af[4], bfr[4];
            #pragma unroll
            for (int mi = 0; mi < 4; mi++)
                af[mi] = *(short8*)&Abuf[(wm + mi * 16 + l15) * 68 + kk * 32 + quad * 8];
            #pragma unroll
            for (int ni = 0; ni < 4; ni++)
                bfr[ni] = *(short8*)&Bbuf[(wn + ni * 16 + l15) * 68 + kk * 32 + quad * 8];
            #pragma unroll
            for (int mi = 0; mi < 4; mi++)
                #pragma unroll
                for (int ni = 0; ni < 4; ni++)
                    acc[mi][ni] = __builtin_amdgcn_mfma_f32_16x16x32_bf16(
                        af[mi], bfr[ni], acc[mi][ni], 0, 0, 0);
        }
    }

    // D row(o) = mo+wm+mi*16+quad*4+r, col(n) = n0+wn+ni*16+l15
    #pragma unroll
    for (int mi = 0; mi < 4; mi++) {
        int rowl = wm + mi * 16 + quad * 4;
        float b4[4], gw4[4], gb4[4];
        #pragma unroll
        for (int r = 0; r < 4; r++) {
            if constexpr (MODE == 4) {
                b4[r] = sc_tile ? bias[mo + rowl + r] : bias2[mo - 512 + rowl + r];
            } else {
                b4[r] = bias[mo + rowl + r];
            }
            if constexpr (MODE == 3) {
                gw4[r] = gw[mo + rowl + r];
                gb4[r] = gb[mo + rowl + r];
            }
        }
        float gs = 0.f, gq = 0.f;
        #pragma unroll
        for (int ni = 0; ni < 4; ni++) {
            int col = n0 + wn + ni * 16 + l15;
            if constexpr (MODE == 3) {
                short4v s4 = *(const short4v*)&sbuf[((size_t)(b * Nc + col)) * 512 + mo + rowl];
                int gl = rowl >> 5;
                #pragma unroll
                for (int r = 0; r < 4; r++) {
                    float v = acc[mi][ni][r] + b4[r];
                    float s = bf2f(s4[r]);
                    float sn = (s - smean[gl]) * sinv[gl] * gw4[r] + gb4[r];
                    float o = v + sn;
                    o = o > 0.f ? o : 0.01f * o;
                    outf[((size_t)b * COUT + mo + rowl + r) * Nc + col] = o;
                }
            } else if constexpr (MODE == 4) {
                short4v sv;
                #pragma unroll
                for (int r = 0; r < 4; r++) {
                    float v = acc[mi][ni][r] + b4[r];
                    if (sc_tile) { gs += v; gq += v * v; }
                    else v = v > 0.f ? v : 0.2f * v;
                    sv[r] = f2bf(v);
                }
                if (sc_tile)
                    *(short4v*)&outb[((size_t)(b * Nc + col)) * 512 + mo + rowl] = sv;
                else
                    *(short4v*)&outb2[((size_t)(b * Nc + col)) * 128 + mo - 512 + rowl] = sv;
            } else {
                short4v sv;
                #pragma unroll
                for (int r = 0; r < 4; r++) {
                    float v = acc[mi][ni][r] + b4[r];
                    if constexpr (MODE == 1) v = v > 0.f ? v : 0.2f * v;
                    if constexpr (MODE == 2) { gs += v; gq += v * v; }
                    sv[r] = f2bf(v);
                }
                *(short4v*)&outb[((size_t)(b * Nc + col)) * COUT + mo + rowl] = sv;
            }
        }
        if ((MODE == 2) || (MODE == 4 && sc_tile)) {
            #pragma unroll
            for (int off = 1; off < 16; off <<= 1) {
                gs += __shfl_xor(gs, off);
                gq += __shfl_xor(gq, off);
            }
            if (l15 == 0) {
                int gl = rowl / GROUP_CH;
                atomicAdd(&sstat[gl * 2 + 0], gs);
                atomicAdd(&sstat[gl * 2 + 1], gq);
            }
        }
    }
    if ((MODE == 2) || (MODE == 4 && sc_tile)) {
        __syncthreads();
        constexpr int NG = 128 / GROUP_CH;
        if (tid < 2 * NG) {
            int g0 = mo / GROUP_CH;
            atomicAdd(&stats[b * 32 + (g0 + (tid >> 1)) * 2 + (tid & 1)], sstat[tid]);
        }
    }
}

// Fused LSE + pool: 64-point tile, 512 threads (8 waves). r11 structure
// (measured 42.0us; r12/r13 occupancy raises were null -> not TLP-bound).
//  A) geo conv (MFMA, precomputed GN) + relu + mean_k  -> m_lds[p][0:128]
//     (4 passes x 16 points; Bbuf = 256 cols = 20KB)
//  B) neighbor gather-mean (opt. folded prev-pool GN)  -> m_lds[p][128:256]
//  C) pool GEMM (PCOUT x 64 x 256) from m_lds, A-frags straight from L2,
//     raw bf16 out + group-stats atomics.
// m_lds channel-groups XOR-swizzled (g ^= p&7) -> all LDS phases <=2-way.
// Total static LDS 58.5KB. PCOUT: 128 (pool1, g8) / 256 (pool2, g16).
template<int PCOUT, int PGROUP>
__launch_bounds__(512)
__global__ void lse_pool_kernel(const float* __restrict__ coords,
                                const int* __restrict__ knn_idx,
                                const float* __restrict__ knn_dist,
                                const short* __restrict__ xprev, // [b][N][128]
                                const short* __restrict__ wpad,  // [128][32]
                                const float* __restrict__ lp,    // geo GN params
                                const float* __restrict__ xst,   // prev stats or null
                                const float* __restrict__ xgw,
                                const float* __restrict__ xgb,
                                float xcnt,
                                const short* __restrict__ pw,    // [PCOUT][256]
                                const float* __restrict__ pb,    // [PCOUT]
                                float* __restrict__ stats,       // [B][32]
                                short* __restrict__ z)           // [b][N][PCOUT]
{
    __shared__ short Bbuf[256 * 40];        // 20 KB: one 16-pt geo sub-tile
    __shared__ short mld[64 * 256];         // 32 KB: m rows, group-swizzled
    __shared__ int   jl[1024];              // [k][p]
    __shared__ float xscs[128], xshs[128];
    __shared__ float sstat[32];

    const int tid = threadIdx.x;
    const int b   = blockIdx.x >> 8;        // Nc/64 = 256 blocks per batch
    const int n0  = (blockIdx.x & 255) * 64;
    const bool norm = (xst != nullptr);
    const int lane = tid & 63, wave = tid >> 6;
    const int l15 = lane & 15, quad = lane >> 4;

    if (tid < 32) sstat[tid] = 0.f;
    if (norm && tid < 128) {                // prev-pool GN fold: 8 ch/group
        int g = tid >> 3;
        float s0 = xst[(b * 16 + g) * 2 + 0];
        float s1 = xst[(b * 16 + g) * 2 + 1];
        float mean = s0 / xcnt;
        float var  = s1 / xcnt - mean * mean;
        float inv  = rsqrtf(var + EPSc);
        float sc_  = inv * xgw[tid];
        xscs[tid] = sc_;
        xshs[tid] = xgb[tid] - mean * sc_;
    }

    // hoisted geo A-frag + GN params (o-tile = wave; 8 waves x 16 = 128 ch)
    short8 af = *(const short8*)(wpad + (wave * 16 + l15) * 32 + quad * 8);
    floatx4 psc = *(const floatx4*)&lp[b * 256 + wave * 16 + quad * 4];
    floatx4 psh = *(const floatx4*)&lp[b * 256 + 128 + wave * 16 + quad * 4];

    const float* cb = coords + (size_t)b * Nc * 3;

    // ---- phase A: geo conv + relu + mean_k -> mld[p][0:128] ----
    #pragma unroll
    for (int pass = 0; pass < 4; pass++) {
        if (tid < 256) {   // build 256 cols (16 points x 16 k): col = tid
            int ptl = tid & 15, k = tid >> 4;
            int p = pass * 16 + ptl;
            int n = n0 + p;
            float cx = cb[n*3+0], cy = cb[n*3+1], cz = cb[n*3+2];
            int   j  = knn_idx[((size_t)b * Nc + n) * Kc + k];
            float nx = cb[j*3+0], ny = cb[j*3+1], nz = cb[j*3+2];
            float d  = knn_dist[((size_t)b * Nc + n) * Kc + k];
            int col = k * 16 + ptl;
            short8 w0, w1, zz;
            w0[0]=f2bf(cx); w0[1]=f2bf(cy); w0[2]=f2bf(cz);
            w0[3]=f2bf(nx); w0[4]=f2bf(ny); w0[5]=f2bf(nz);
            w0[6]=f2bf(cx-nx); w0[7]=f2bf(cy-ny);
            w1[0]=f2bf(cz-nz); w1[1]=f2bf(d);
            #pragma unroll
            for (int i = 2; i < 8; i++) w1[i] = 0;
            #pragma unroll
            for (int i = 0; i < 8; i++) zz[i] = 0;
            *(short8*)&Bbuf[col * 40 + 0]  = w0;
            *(short8*)&Bbuf[col * 40 + 8]  = w1;
            *(short8*)&Bbuf[col * 40 + 16] = zz;
            *(short8*)&Bbuf[col * 40 + 24] = zz;
            jl[k * 64 + p] = j;
        }
        __syncthreads();
        {
            float s4[4] = {0.f, 0.f, 0.f, 0.f};
            #pragma unroll
            for (int nb = 0; nb < 8; nb++) {
                short8 f0 = *(short8*)&Bbuf[((nb*2+0)*16 + l15) * 40 + quad * 8];
                short8 f1 = *(short8*)&Bbuf[((nb*2+1)*16 + l15) * 40 + quad * 8];
                floatx4 a0 = __builtin_amdgcn_mfma_f32_16x16x32_bf16(
                    af, f0, (floatx4){0.f, 0.f, 0.f, 0.f}, 0, 0, 0);
                floatx4 a1 = __builtin_amdgcn_mfma_f32_16x16x32_bf16(
                    af, f1, (floatx4){0.f, 0.f, 0.f, 0.f}, 0, 0, 0);
                #pragma unroll
                for (int r = 0; r < 4; r++) {
                    float v0 = a0[r] * psc[r] + psh[r];
                    float v1 = a1[r] * psc[r] + psh[r];
                    s4[r] += (v0 > 0.f ? v0 : 0.f) + (v1 > 0.f ? v1 : 0.f);
                }
            }
            // D col = point l15, rows o = wave*16 + quad*4 + r
            int p = pass * 16 + l15;
            int g = wave * 2 + (quad >> 1);          // ch group (0..15)
            short4v sv;
            #pragma unroll
            for (int r = 0; r < 4; r++) sv[r] = f2bf(s4[r] * (1.f / 16.f));
            *(short4v*)&mld[p * 256 + ((g ^ (p & 7)) << 3) + (quad & 1) * 4] = sv;
        }
        __syncthreads();
    }

    // ---- phase B: gather-mean -> mld[p][128:256] (jl complete) ----
    {
        const int tp = tid >> 4, cs = tid & 15;     // tp in [0,32)
        float sc8[8], sh8[8];
        if (norm) {
            #pragma unroll
            for (int i = 0; i < 8; i++) { sc8[i] = xscs[cs*8+i]; sh8[i] = xshs[cs*8+i]; }
        }
        #pragma unroll
        for (int pp = 0; pp < 2; pp++) {
            int p = tp + pp * 32;
            float acc8[8];
            #pragma unroll
            for (int i = 0; i < 8; i++) acc8[i] = 0.f;
            #pragma unroll
            for (int k = 0; k < 16; k++) {
                int j = jl[k * 64 + p];
                short8 v = *(const short8*)&xprev[((size_t)(b * Nc + j)) * 128 + cs * 8];
                if (norm) {
                    #pragma unroll
                    for (int i = 0; i < 8; i++) {
                        float t = bf2f(v[i]) * sc8[i] + sh8[i];
                        acc8[i] += t > 0.f ? t : 0.f;
                    }
                } else {
                    #pragma unroll
                    for (int i = 0; i < 8; i++) acc8[i] += bf2f(v[i]);
                }
            }
            short8 sv;
            #pragma unroll
            for (int i = 0; i < 8; i++) sv[i] = f2bf(acc8[i] * (1.f / 16.f));
            int g = 16 + cs;
            *(short8*)&mld[p * 256 + ((g ^ (p & 7)) << 3)] = sv;
        }
    }
    __syncthreads();

    // ---- phase C: pool GEMM (PCOUT x 64pts x 256ch) ----
    constexpr int NOT = PCOUT / 128;               // o-tiles per wave (1 or 2)
    #pragma unroll
    for (int oi = 0; oi < NOT; oi++) {
        const int ot = wave + oi * 8;
        short8 afk[8];
        #pragma unroll
        for (int ks = 0; ks < 8; ks++)
            afk[ks] = *(const short8*)(pw + ((size_t)(ot * 16 + l15)) * 256 + ks * 32 + quad * 8);
        floatx4 acc[4];
        #pragma unroll
        for (int nt = 0; nt < 4; nt++) acc[nt] = (floatx4){0.f, 0.f, 0.f, 0.f};
        #pragma unroll
        for (int ks = 0; ks < 8; ks++) {
            #pragma unroll
            for (int nt = 0; nt < 4; nt++) {
                int p = nt * 16 + l15;
                int g = ks * 4 + quad;
                short8 bfr = *(short8*)&mld[p * 256 + ((g ^ (p & 7)) << 3)];
                acc[nt] = __builtin_amdgcn_mfma_f32_16x16x32_bf16(
                    afk[ks], bfr, acc[nt], 0, 0, 0);
            }
        }
        floatx4 b4 = *(const floatx4*)&pb[ot * 16 + quad * 4];
        float gs = 0.f, gq = 0.f;
        #pragma unroll
        for (int nt = 0; nt < 4; nt++) {
            int col = n0 + nt * 16 + l15;
            short4v sv;
            #pragma unroll
            for (int r = 0; r < 4; r++) {
                float v = acc[nt][r] + b4[r];
                gs += v; gq += v * v;
                sv[r] = f2bf(v);
            }
            *(short4v*)&z[((size_t)(b * Nc + col)) * PCOUT + ot * 16 + quad * 4] = sv;
        }
        #pragma unroll
        for (int off = 1; off < 16; off <<= 1) {
            gs += __shfl_xor(gs, off);
            gq += __shfl_xor(gq, off);
        }
        if (l15 == 0) {
            int gl = (ot * 16 + quad * 4) / PGROUP;
            atomicAdd(&sstat[gl * 2 + 0], gs);
            atomicAdd(&sstat[gl * 2 + 1], gq);
        }
    }
    __syncthreads();
    if (tid < 32) atomicAdd(&stats[b * 32 + tid], sstat[tid]);
}

extern "C" void kernel_launch(void* const* d_in, const int* in_sizes, int n_in,
                              void* d_out, int out_size, void* d_ws, size_t ws_size,
                              hipStream_t stream)
{
    const float* coords   = (const float*)d_in[0];
    const float* features = (const float*)d_in[1];
    const float* knn_dist = (const float*)d_in[2];
    const int*   knn_idx  = (const int*)  d_in[3];
    const float* w1       = (const float*)d_in[4];
    const float* b1       = (const float*)d_in[5];
    const float* lse1_w   = (const float*)d_in[6];
    const float* lse1_b   = (const float*)d_in[7];
    const float* lse1_gw  = (const float*)d_in[8];
    const float* lse1_gb  = (const float*)d_in[9];
    const float* pool1_w  = (const float*)d_in[10];
    const float* pool1_b  = (const float*)d_in[11];
    const float* pool1_gw = (const float*)d_in[12];
    const float* pool1_gb = (const float*)d_in[13];
    const float* lse2_w   = (const float*)d_in[14];
    const float* lse2_b   = (const float*)d_in[15];
    const float* lse2_gw  = (const float*)d_in[16];
    const float* lse2_gb  = (const float*)d_in[17];
    const float* pool2_w  = (const float*)d_in[18];
    const float* pool2_b  = (const float*)d_in[19];
    const float* pool2_gw = (const float*)d_in[20];
    const float* pool2_gb = (const float*)d_in[21];
    const float* mlp2_w   = (const float*)d_in[22];
    const float* mlp2_b   = (const float*)d_in[23];
    const float* sc_w     = (const float*)d_in[24];
    const float* sc_b     = (const float*)d_in[25];
    const float* sc_gw    = (const float*)d_in[26];
    const float* sc_gb    = (const float*)d_in[27];
    (void)in_sizes; (void)n_in; (void)out_size; (void)ws_size;

    float* ST = (float*)d_ws;           // 2048 floats
    float* ST_SC  = ST + 0;
    float* ST_P1  = ST + 64;
    float* ST_P2  = ST + 128;
    float* ST_GEO = ST + 256;           // B x 65
    float* ST_LP  = ST + 512;           // [stage][b][{psc,psh}x128]
    short* W16 = (short*)(ST + 2048);
    short* P1Wb = W16 + OW_P1W;
    short* P2Wb = W16 + OW_P2W;
    short* M2Wb = W16 + OW_M2W;
    short* SCWb = W16 + OW_SCW;         // rows 0..511 sc, 512..639 w1
    short* L1Wb = W16 + OW_L1W;
    short* L2Wb = W16 + OW_L2W;
    short* FB   = W16 + OW_FB;
    short* X1B  = W16 + OW_X1;
    short* Z1   = W16 + OW_Z1;
    short* Z2   = W16 + OW_Z2;
    short* SB   = W16 + OW_S;
    float* out  = (float*)d_out;

    // merged prep (weights->bf16, ST zero) + feat transpose
    prep_feat_kernel<<<PREP_BLKS + FEAT_BLKS, 256, 0, stream>>>(
        pool1_w, pool2_w, mlp2_w, sc_w, w1, lse1_w, lse2_w, W16, ST,
        features, FB);
    geo_reduce_kernel<<<dim3(256, Bc), 256, 0, stream>>>(
        coords, knn_idx, knn_dist, ST_GEO);
    lse_param_kernel<<<1, 512, 0, stream>>>(
        ST_GEO, lse1_w, lse1_b, lse1_gw, lse1_gb,
        lse2_w, lse2_b, lse2_gw, lse2_gb, ST_LP);

    // merged sc (512, raw bf16 + stats, group=32ch) + mlp1 (128, leaky 0.2)
    gemm_conv<128,640,32,4><<<dim3(Nc/128, 5, Bc), 256, 0, stream>>>(
        SCWb, FB, sc_b, SB, nullptr, ST_SC, nullptr, nullptr, nullptr, nullptr, 0.f,
        nullptr, nullptr, nullptr, 0.f, b1, X1B);
    // fused lse1 + pool1 (128 out, group 8): X1B gather raw, stats -> ST_P1
    lse_pool_kernel<128,8><<<Bc * Nc / 64, 512, 0, stream>>>(
        coords, knn_idx, knn_dist, X1B, L1Wb, ST_LP,
        nullptr, nullptr, nullptr, 0.f,
        P1Wb, pool1_b, ST_P1, Z1);
    // fused lse2 + pool2 (256 out, group 16): Z1 gather + pool1-GN fold,
    // stats -> ST_P2
    lse_pool_kernel<256,16><<<Bc * Nc / 64, 512, 0, stream>>>(
        coords, knn_idx, knn_dist, Z1, L2Wb, ST_LP + 512,
        ST_P1, pool1_gw, pool1_gb, (float)(8 * Nc),
        P2Wb, pool2_b, ST_P2, Z2);
    // final: mlp2(GN+relu(Z2) folded into staging) + GN(S) -> leaky 0.01 -> f32
    gemm_conv<256,512,32,3><<<dim3(Nc/128, 4, Bc), 256, 0, stream>>>(
        M2Wb, Z2, mlp2_b, nullptr, out, nullptr, SB, ST_SC, sc_gw, sc_gb,
        (float)(32 * Nc), ST_P2, pool2_gw, pool2_gb, (float)(16 * Nc),
        nullptr, nullptr);
}